// Round 7
// baseline (146.384 us; speedup 1.0000x reference)
//
#include <hip/hip_runtime.h>
#include <hip/hip_bf16.h>
#include <stdint.h>

typedef __attribute__((ext_vector_type(4))) float f32x4;
typedef __attribute__((ext_vector_type(8))) __bf16 bf16x8;
typedef __attribute__((ext_vector_type(4))) __bf16 bf16x4;

#define DEVI __device__ __forceinline__

static constexpr int S_  = 2048;
static constexpr int D_  = 1024;
static constexpr int H_  = 16;
static constexpr int HD_ = 64;
static constexpr int M_  = 2 * S_;   // B*S = 4096 token rows
static constexpr float SCL2 = 0.18033688f;  // 0.125 * log2(e)

DEVI void gload_lds16(const void* gsrc, void* ldst) {
  __builtin_amdgcn_global_load_lds(
      (__attribute__((address_space(1))) void*)(void*)gsrc,
      (__attribute__((address_space(3))) void*)ldst, 16, 0, 0);
}

DEVI float fexp2(float x) {
  float r;
  asm("v_exp_f32 %0, %1" : "=v"(r) : "v"(x));
  return r;
}

// One fused conversion kernel: x + 4 weights fp32->bf16, plus RoPE table.
__global__ __launch_bounds__(256) void cvt_all_kernel(
    const float* __restrict__ x, const float* __restrict__ wq,
    const float* __restrict__ wk, const float* __restrict__ wv,
    const float* __restrict__ wo,
    __bf16* __restrict__ xb, __bf16* __restrict__ wqb,
    __bf16* __restrict__ wkb, __bf16* __restrict__ wvb,
    __bf16* __restrict__ wob, float* __restrict__ tab) {
  int blk = blockIdx.x;
  if (blk < 8192) {
    int i = blk * 256 + threadIdx.x;     // float4 index
    const float* src; __bf16* dst; int off;
    if (i < (1 << 20))                      { src = x;  dst = xb;  off = 0; }
    else if (i < (1 << 20) + (1 << 18))     { src = wq; dst = wqb; off = (1 << 20); }
    else if (i < (1 << 20) + 2 * (1 << 18)) { src = wk; dst = wkb; off = (1 << 20) + (1 << 18); }
    else if (i < (1 << 20) + 3 * (1 << 18)) { src = wv; dst = wvb; off = (1 << 20) + 2 * (1 << 18); }
    else                                    { src = wo; dst = wob; off = (1 << 20) + 3 * (1 << 18); }
    int j = i - off;
    float4 v = reinterpret_cast<const float4*>(src)[j];
    bf16x4 o;
    o[0] = (__bf16)v.x; o[1] = (__bf16)v.y; o[2] = (__bf16)v.z; o[3] = (__bf16)v.w;
    reinterpret_cast<bf16x4*>(dst)[j] = o;
  } else {
    int i = (blk - 8192) * 256 + threadIdx.x;   // 0..65535 = S*32
    int s = i >> 5, f = i & 31;
    float freq = powf(10000.0f, -(float)(2 * f) / (float)HD_);
    float ang = (float)s * freq;
    tab[2 * i]     = cosf(ang);
    tab[2 * i + 1] = sinf(ang);
  }
}

// ---------------------------------------------------------------------------
// QKV GEMM: m97 128x128 BK=32 structure (round-3 proven, 53.6us) + counted-
// vmcnt double-buffer (pattern proven in attn round 6): per iter
// compute buf[kt&1] -> s_barrier -> stage tile kt+2 into buf[kt&1] ->
// vmcnt(4) [tile kt+1 landed; issued a full iter ago] -> s_barrier.
// No __syncthreads in the K-loop (it force-drains vmcnt).
// grid (32, 8, 3): z selects Q/K/V weight; epilogue fuses RoPE + head-split.
// ---------------------------------------------------------------------------
__global__ __launch_bounds__(256) void gemm_qkv(
    const __bf16* __restrict__ A, const __bf16* __restrict__ W0,
    const __bf16* __restrict__ W1, const __bf16* __restrict__ W2,
    __bf16* __restrict__ Cq, __bf16* __restrict__ Ck, __bf16* __restrict__ Cv,
    const float* __restrict__ tab) {
  __shared__ __attribute__((aligned(16))) __bf16 As[2][128 * 32];
  __shared__ __attribute__((aligned(16))) __bf16 Bs[2][128 * 32];
  const int tid  = threadIdx.x;
  const int lane = tid & 63;
  const int wv   = tid >> 6;
  const int m0 = blockIdx.x * 128;
  const int n0 = blockIdx.y * 128;
  const int z  = blockIdx.z;
  const __bf16* W = (z == 0) ? W0 : (z == 1 ? W1 : W2);
  const __bf16* Ab = A + (size_t)m0 * 1024;
  const __bf16* Wb = W + (size_t)n0 * 1024;
  const int wm = (wv >> 1) * 64, wn = (wv & 1) * 64;
  const int arow = lane & 15;
  const int kgrp = (lane >> 4) * 8;

#define STAGEG(T, AB, BB)                                                    \
  do {                                                                       \
    _Pragma("unroll") for (int j = 0; j < 2; ++j) {                          \
      int c   = (wv * 2 + j) * 64 + lane;                                    \
      int row = c >> 2;                                                      \
      int kc  = (c & 3) * 8;                                                 \
      gload_lds16(Ab + (size_t)row * 1024 + (T) * 32 + kc,                   \
                  (AB) + (wv * 2 + j) * 512);                                \
      gload_lds16(Wb + (size_t)row * 1024 + (T) * 32 + kc,                   \
                  (BB) + (wv * 2 + j) * 512);                                \
    }                                                                        \
  } while (0)

  f32x4 acc[4][4];
#pragma unroll
  for (int i = 0; i < 4; i++)
#pragma unroll
    for (int j = 0; j < 4; j++) acc[i][j] = f32x4{0.f, 0.f, 0.f, 0.f};

  // prologue: tiles 0 and 1 in flight; vmcnt(4) -> tile 0 landed
  STAGEG(0, As[0], Bs[0]);
  STAGEG(1, As[1], Bs[1]);
  asm volatile("s_waitcnt vmcnt(4)" ::: "memory");
  __builtin_amdgcn_s_barrier();

  for (int kt = 0; kt < 32; ++kt) {
    const int cur = kt & 1;
    bf16x8 af[4], bw[4];
#pragma unroll
    for (int i = 0; i < 4; i++)
      af[i] = *reinterpret_cast<const bf16x8*>(As[cur] + (wm + i * 16 + arow) * 32 + kgrp);
#pragma unroll
    for (int i = 0; i < 4; i++)
      bw[i] = *reinterpret_cast<const bf16x8*>(Bs[cur] + (wn + i * 16 + arow) * 32 + kgrp);
    __builtin_amdgcn_s_setprio(1);
#pragma unroll
    for (int i = 0; i < 4; i++)
#pragma unroll
      for (int j = 0; j < 4; j++)
        acc[i][j] = __builtin_amdgcn_mfma_f32_16x16x32_bf16(af[i], bw[j], acc[i][j], 0, 0, 0);
    __builtin_amdgcn_s_setprio(0);

    // all waves done reading buf[cur]; refill it with tile kt+2
    __builtin_amdgcn_s_barrier();
    if (kt < 30) {
      STAGEG(kt + 2, As[cur], Bs[cur]);
      asm volatile("s_waitcnt vmcnt(4)" ::: "memory");   // tile kt+1 landed
    } else if (kt == 30) {
      asm volatile("s_waitcnt vmcnt(0)" ::: "memory");   // last tile landed
    }
    __builtin_amdgcn_s_barrier();
  }
#undef STAGEG

  // epilogue: RoPE + head-split. C/D: col=lane&15 (n), row=(lane>>4)*4+r (m)
#pragma unroll
  for (int i = 0; i < 4; i++) {
#pragma unroll
    for (int j = 0; j < 4; j++) {
#pragma unroll
      for (int r = 0; r < 4; r++) {
        int m = m0 + wm + i * 16 + (lane >> 4) * 4 + r;
        int n = n0 + wn + j * 16 + arow;
        float v = acc[i][j][r];
        int bb = m >> 11, srow = m & (S_ - 1);
        int h = n >> 6, d = n & 63;
        size_t oidx = ((size_t)(bb * H_ + h) * S_ + srow) * HD_ + d;
        float other = __shfl_xor(v, 1, 64);   // n bit0 == lane bit0
        if (z == 2) {
          Cv[oidx] = (__bf16)v;
        } else {
          int fq = d >> 1;
          float2 cssn = *reinterpret_cast<const float2*>(tab + (srow * 32 + fq) * 2);
          float rv = (d & 1) ? (other * cssn.y + v * cssn.x)
                             : (v * cssn.x - other * cssn.y);
          if (z == 0) rv *= SCL2;   // pre-scale Q: logits in exp2 domain
          ((z == 0) ? Cq : Ck)[oidx] = (__bf16)rv;
        }
      }
    }
  }
}

// O-projection: same m97 BK=32 + counted-vmcnt dbuf; fp32 out.
__global__ __launch_bounds__(256) void gemm_bt0(
    const __bf16* __restrict__ A, const __bf16* __restrict__ W0,
    float* __restrict__ Cf) {
  __shared__ __attribute__((aligned(16))) __bf16 As[2][128 * 32];
  __shared__ __attribute__((aligned(16))) __bf16 Bs[2][128 * 32];
  const int tid  = threadIdx.x;
  const int lane = tid & 63;
  const int wv   = tid >> 6;
  const int m0 = blockIdx.x * 128;
  const int n0 = blockIdx.y * 128;
  const __bf16* Ab = A + (size_t)m0 * 1024;
  const __bf16* Wb = W0 + (size_t)n0 * 1024;
  const int wm = (wv >> 1) * 64, wn = (wv & 1) * 64;
  const int arow = lane & 15;
  const int kgrp = (lane >> 4) * 8;

#define STAGEG(T, AB, BB)                                                    \
  do {                                                                       \
    _Pragma("unroll") for (int j = 0; j < 2; ++j) {                          \
      int c   = (wv * 2 + j) * 64 + lane;                                    \
      int row = c >> 2;                                                      \
      int kc  = (c & 3) * 8;                                                 \
      gload_lds16(Ab + (size_t)row * 1024 + (T) * 32 + kc,                   \
                  (AB) + (wv * 2 + j) * 512);                                \
      gload_lds16(Wb + (size_t)row * 1024 + (T) * 32 + kc,                   \
                  (BB) + (wv * 2 + j) * 512);                                \
    }                                                                        \
  } while (0)

  f32x4 acc[4][4];
#pragma unroll
  for (int i = 0; i < 4; i++)
#pragma unroll
    for (int j = 0; j < 4; j++) acc[i][j] = f32x4{0.f, 0.f, 0.f, 0.f};

  STAGEG(0, As[0], Bs[0]);
  STAGEG(1, As[1], Bs[1]);
  asm volatile("s_waitcnt vmcnt(4)" ::: "memory");
  __builtin_amdgcn_s_barrier();

  for (int kt = 0; kt < 32; ++kt) {
    const int cur = kt & 1;
    bf16x8 af[4], bw[4];
#pragma unroll
    for (int i = 0; i < 4; i++)
      af[i] = *reinterpret_cast<const bf16x8*>(As[cur] + (wm + i * 16 + arow) * 32 + kgrp);
#pragma unroll
    for (int i = 0; i < 4; i++)
      bw[i] = *reinterpret_cast<const bf16x8*>(Bs[cur] + (wn + i * 16 + arow) * 32 + kgrp);
    __builtin_amdgcn_s_setprio(1);
#pragma unroll
    for (int i = 0; i < 4; i++)
#pragma unroll
      for (int j = 0; j < 4; j++)
        acc[i][j] = __builtin_amdgcn_mfma_f32_16x16x32_bf16(af[i], bw[j], acc[i][j], 0, 0, 0);
    __builtin_amdgcn_s_setprio(0);

    __builtin_amdgcn_s_barrier();
    if (kt < 30) {
      STAGEG(kt + 2, As[cur], Bs[cur]);
      asm volatile("s_waitcnt vmcnt(4)" ::: "memory");
    } else if (kt == 30) {
      asm volatile("s_waitcnt vmcnt(0)" ::: "memory");
    }
    __builtin_amdgcn_s_barrier();
  }
#undef STAGEG

#pragma unroll
  for (int i = 0; i < 4; i++)
#pragma unroll
    for (int j = 0; j < 4; j++)
#pragma unroll
      for (int r = 0; r < 4; r++) {
        int m = m0 + wm + i * 16 + (lane >> 4) * 4 + r;
        int n = n0 + wn + j * 16 + arow;
        Cf[(size_t)m * D_ + n] = acc[i][j][r];
      }
}

// V [bh][s][d=64] -> Vt [bh][d][s].  Tile 64s x 64d per block.
__global__ __launch_bounds__(256) void vtrans_kernel(
    const __bf16* __restrict__ V, __bf16* __restrict__ Vt) {
  __shared__ __attribute__((aligned(16))) char T[64 * 144]; // row d, 144B stride
  const int bh = blockIdx.y, s0 = blockIdx.x * 64;
  const __bf16* Vb = V + (size_t)bh * S_ * HD_;
  __bf16* Vtb = Vt + (size_t)bh * HD_ * S_;
  const int tid = threadIdx.x;
#pragma unroll
  for (int j = 0; j < 2; ++j) {
    int c = tid + j * 256;            // s = c>>3, dc = c&7
    int s = c >> 3, dc = c & 7;
    bf16x8 v = *reinterpret_cast<const bf16x8*>(Vb + (size_t)(s0 + s) * HD_ + dc * 8);
#pragma unroll
    for (int e = 0; e < 8; ++e) {
      int d = dc * 8 + e;
      int byt = (d * 144 + s * 2) ^ ((dc & 7) << 4);   // spread banks by dc
      *reinterpret_cast<__bf16*>(T + byt) = v[e];
    }
  }
  __syncthreads();
#pragma unroll
  for (int j = 0; j < 2; ++j) {
    int c = tid + j * 256;            // d = c>>3, sc = c&7
    int d = c >> 3, sc = c & 7;
    int byt = (d * 144 + sc * 16) ^ (((d >> 3) & 7) << 4);
    bf16x8 o = *reinterpret_cast<const bf16x8*>(T + byt);
    *reinterpret_cast<bf16x8*>(Vtb + (size_t)d * S_ + s0 + sc * 8) = o;
  }
}

// Flash attention, causal. Grid: (bh=32, pr=16). Block: 4 waves x 16 q-rows,
// paired q-tiles (pr, 31-pr) => uniform 33 kv-iters per block.
// Swapped QK^T (P lane-local) + counted-vmcnt staging pipeline.
__global__ __launch_bounds__(256) void attn_kernel(
    const __bf16* __restrict__ Q, const __bf16* __restrict__ K,
    const __bf16* __restrict__ Vt, __bf16* __restrict__ O) {
  __shared__ __attribute__((aligned(16))) __bf16 Ks[2][64 * 64];
  __shared__ __attribute__((aligned(16))) __bf16 Vs[2][64 * 64];
  const int tid = threadIdx.x, lane = tid & 63, wv = tid >> 6;
  const int bh = blockIdx.x;   // stride-32 linear ids: all pr of one bh share an XCD
  const int pr = blockIdx.y;
  const int b = bh >> 4, h = bh & 15;
  const __bf16* Qb  = Q  + (size_t)bh * S_ * HD_;
  const __bf16* Kb  = K  + (size_t)bh * S_ * HD_;
  const __bf16* Vtb = Vt + (size_t)bh * HD_ * S_;
  const int arow = lane & 15, g = lane >> 4;

#define STAGE(K0, BK_, BV_)                                                   \
  do {                                                                        \
    _Pragma("unroll") for (int j = 0; j < 2; ++j) {                           \
      int G = (wv * 2 + j) * 64 + lane;                                       \
      int row = G >> 3, qq = G & 7;                                           \
      int qs = qq ^ (row & 7);                                                \
      int ctp = row >> 4, rw = row & 15;                                      \
      int kph = ((ctp >> 1) << 5) + ((rw >> 2) << 3) + ((ctp & 1) << 2)       \
                + (rw & 3);                                                   \
      gload_lds16(Kb + (size_t)((K0) + kph) * HD_ + qs * 8,                   \
                  (BK_) + (wv * 2 + j) * 512);                                \
      gload_lds16(Vtb + (size_t)row * S_ + (K0) + qs * 8,                     \
                  (BV_) + (wv * 2 + j) * 512);                                \
    }                                                                         \
  } while (0)

  for (int seg = 0; seg < 2; ++seg) {
    const int qt = (seg == 0) ? pr : 31 - pr;
    const int q0 = qt * 64;
    const int nkv = qt + 1;
    const int qw = q0 + wv * 16;
    const int qg = qw + arow;          // this thread's q-row

    bf16x8 aq[2];
#pragma unroll
    for (int j = 0; j < 2; j++)
      aq[j] = *reinterpret_cast<const bf16x8*>(
          Qb + (size_t)(qw + arow) * HD_ + j * 32 + g * 8);

    f32x4 po[4];
#pragma unroll
    for (int dt = 0; dt < 4; dt++) po[dt] = f32x4{0.f, 0.f, 0.f, 0.f};
    float mrow = -1e30f, lrow = 0.f;

    // prologue: stage tiles 0 and 1 (clamped); vmcnt(4) -> tile 0 landed
    STAGE(0, Ks[0], Vs[0]);
    {
      int t1 = (nkv > 1) ? 64 : 0;
      STAGE(t1, Ks[1], Vs[1]);
    }
    asm volatile("s_waitcnt vmcnt(4)" ::: "memory");
    __builtin_amdgcn_s_barrier();

    for (int kt = 0; kt < nkv; ++kt) {
      const int k0 = kt * 64;
      const int cur = kt & 1;
      const __bf16* Kc = Ks[cur];
      const __bf16* Vc = Vs[cur];

      // S^T = K Q^T : D[key][q], 8 MFMA
      f32x4 sc4[4];
      __builtin_amdgcn_s_setprio(1);
#pragma unroll
      for (int ct = 0; ct < 4; ct++) {
        sc4[ct] = f32x4{0.f, 0.f, 0.f, 0.f};
        int L = ct * 16 + arow;
#pragma unroll
        for (int j2 = 0; j2 < 2; j2++) {
          int byt = (L * 128 + j2 * 64 + g * 16) ^ ((L & 7) << 4);
          bf16x8 kb = *reinterpret_cast<const bf16x8*>((const char*)Kc + byt);
          sc4[ct] = __builtin_amdgcn_mfma_f32_16x16x32_bf16(kb, aq[j2], sc4[ct], 0, 0, 0);
        }
      }
      __builtin_amdgcn_s_setprio(0);

      // causal mask (diagonal tile only)
      const bool full = (kt < nkv - 1);
      if (!full) {
#pragma unroll
        for (int ct = 0; ct < 4; ct++) {
          int kb0 = k0 + ((ct >> 1) << 5) + ((ct & 1) << 2) + g * 8;
#pragma unroll
          for (int r = 0; r < 4; r++)
            if (kb0 + r > qg) sc4[ct][r] = -1e30f;
        }
      }

      // in-register online softmax (one q-row per lane)
      float mx = -1e30f;
#pragma unroll
      for (int ct = 0; ct < 4; ct++)
#pragma unroll
        for (int r = 0; r < 4; r++) mx = fmaxf(mx, sc4[ct][r]);
      mx = fmaxf(mx, __shfl_xor(mx, 16, 64));
      mx = fmaxf(mx, __shfl_xor(mx, 32, 64));

      bool noskip = !__all(mx <= mrow + 11.0f);
      if (noskip) {
        float mnew = fmaxf(mrow, mx);
        float corr = fexp2(mrow - mnew);
        mrow = mnew;
        lrow *= corr;
#pragma unroll
        for (int dt = 0; dt < 4; dt++)
#pragma unroll
          for (int r = 0; r < 4; r++) po[dt][r] *= corr;
      }

      float rs = 0.f;
      float pv[4][4];
#pragma unroll
      for (int ct = 0; ct < 4; ct++)
#pragma unroll
        for (int r = 0; r < 4; r++) {
          float e = fexp2(sc4[ct][r] - mrow);
          pv[ct][r] = e;
          rs += e;
        }
      rs += __shfl_xor(rs, 16, 64);
      rs += __shfl_xor(rs, 32, 64);
      lrow += rs;

      // pack P: pb[j2] holds physical keys j2*32 + g*8 .. +7 (lane-local)
      bf16x8 pb[2];
#pragma unroll
      for (int j2 = 0; j2 < 2; j2++) {
#pragma unroll
        for (int r = 0; r < 4; r++) {
          pb[j2][r]     = (__bf16)pv[2 * j2][r];
          pb[j2][4 + r] = (__bf16)pv[2 * j2 + 1][r];
        }
      }

      // O^T += V^T P^T : po[dt] = D[d][q], d = dt*16 + g*4 + r, q = arow
      __builtin_amdgcn_s_setprio(1);
#pragma unroll
      for (int dt = 0; dt < 4; dt++) {
        int d = dt * 16 + arow;
#pragma unroll
        for (int j2 = 0; j2 < 2; j2++) {
          int byv = (d * 128 + j2 * 64 + g * 16) ^ ((d & 7) << 4);
          bf16x8 vb = *reinterpret_cast<const bf16x8*>((const char*)Vc + byv);
          po[dt] = __builtin_amdgcn_mfma_f32_16x16x32_bf16(vb, pb[j2], po[dt], 0, 0, 0);
        }
      }
      __builtin_amdgcn_s_setprio(0);

      // pipeline tail: all waves done reading buf[cur], then stage kt+2
      __builtin_amdgcn_s_barrier();
      if (kt < nkv - 1) {
        int nx = kt + 2;
        if (nx > nkv - 1) nx = nkv - 1;     // clamp: uniform 4-load count
        STAGE(nx * 64, Ks[cur], Vs[cur]);   // overwrite retired buffer
        asm volatile("s_waitcnt vmcnt(4)" ::: "memory");  // tile kt+1 landed
      } else {
        asm volatile("s_waitcnt vmcnt(0)" ::: "memory");  // drain for next seg
      }
      __builtin_amdgcn_s_barrier();
    }

    float inv = __builtin_amdgcn_rcpf(lrow);
#pragma unroll
    for (int dt = 0; dt < 4; dt++) {
      bf16x4 o4;
#pragma unroll
      for (int r = 0; r < 4; r++) o4[r] = (__bf16)(po[dt][r] * inv);
      *reinterpret_cast<bf16x4*>(
          O + (size_t)(b * S_ + qg) * D_ + h * HD_ + dt * 16 + g * 4) = o4;
    }
  }
#undef STAGE
}

extern "C" void kernel_launch(void* const* d_in, const int* in_sizes, int n_in,
                              void* d_out, int out_size, void* d_ws, size_t ws_size,
                              hipStream_t stream) {
  const float* x  = (const float*)d_in[0];
  const float* wq = (const float*)d_in[1];
  const float* wk = (const float*)d_in[2];
  const float* wv = (const float*)d_in[3];
  const float* wo = (const float*)d_in[4];
  float* out = (float*)d_out;

  char* w = (char*)d_ws;
  __bf16* xb  = (__bf16*)(w);                    // 8 MB (reused as Vt later)
  __bf16* wqb = (__bf16*)(w + (8u  << 20));      // 2 MB each
  __bf16* wkb = (__bf16*)(w + (10u << 20));
  __bf16* wvb = (__bf16*)(w + (12u << 20));
  __bf16* wob = (__bf16*)(w + (14u << 20));
  __bf16* qws = (__bf16*)(w + (16u << 20));      // 8 MB each, [B][H][S][hd]
  __bf16* kws = (__bf16*)(w + (24u << 20));
  __bf16* vws = (__bf16*)(w + (32u << 20));
  __bf16* aws = (__bf16*)(w + (40u << 20));      // attn out, [token][feature]
  float*  tab = (float*)(w + (48u << 20));       // 512 KB rope table
  __bf16* vtw = xb;                              // Vt overlays xb (dead after QKV)

  cvt_all_kernel<<<8448, 256, 0, stream>>>(x, wq, wk, wv, wo,
                                           xb, wqb, wkb, wvb, wob, tab);
  gemm_qkv<<<dim3(32, 8, 3), 256, 0, stream>>>(xb, wqb, wkb, wvb,
                                               qws, kws, vws, tab);
  vtrans_kernel<<<dim3(S_ / 64, 2 * H_), 256, 0, stream>>>(vws, vtw);
  attn_kernel<<<dim3(2 * H_, S_ / 128), 256, 0, stream>>>(qws, kws, vtw, aws);
  gemm_bt0<<<dim3(M_ / 128, D_ / 128), 256, 0, stream>>>(aws, wob, out);
}

// Round 8
// 125.759 us; speedup vs baseline: 1.1640x; 1.1640x over previous
//
#include <hip/hip_runtime.h>
#include <hip/hip_bf16.h>
#include <stdint.h>

typedef __attribute__((ext_vector_type(4))) float f32x4;
typedef __attribute__((ext_vector_type(8))) __bf16 bf16x8;
typedef __attribute__((ext_vector_type(4))) __bf16 bf16x4;

#define DEVI __device__ __forceinline__

static constexpr int S_  = 2048;
static constexpr int D_  = 1024;
static constexpr int H_  = 16;
static constexpr int HD_ = 64;
static constexpr int M_  = 2 * S_;   // B*S = 4096 token rows
static constexpr float SCL2 = 0.18033688f;  // 0.125 * log2(e)

DEVI void gload_lds16(const void* gsrc, void* ldst) {
  __builtin_amdgcn_global_load_lds(
      (__attribute__((address_space(1))) void*)(void*)gsrc,
      (__attribute__((address_space(3))) void*)ldst, 16, 0, 0);
}

DEVI float fexp2(float x) {
  float r;
  asm("v_exp_f32 %0, %1" : "=v"(r) : "v"(x));
  return r;
}

// One fused conversion kernel: x + 4 weights fp32->bf16, plus RoPE table.
__global__ __launch_bounds__(256) void cvt_all_kernel(
    const float* __restrict__ x, const float* __restrict__ wq,
    const float* __restrict__ wk, const float* __restrict__ wv,
    const float* __restrict__ wo,
    __bf16* __restrict__ xb, __bf16* __restrict__ wqb,
    __bf16* __restrict__ wkb, __bf16* __restrict__ wvb,
    __bf16* __restrict__ wob, float* __restrict__ tab) {
  int blk = blockIdx.x;
  if (blk < 8192) {
    int i = blk * 256 + threadIdx.x;     // float4 index
    const float* src; __bf16* dst; int off;
    if (i < (1 << 20))                      { src = x;  dst = xb;  off = 0; }
    else if (i < (1 << 20) + (1 << 18))     { src = wq; dst = wqb; off = (1 << 20); }
    else if (i < (1 << 20) + 2 * (1 << 18)) { src = wk; dst = wkb; off = (1 << 20) + (1 << 18); }
    else if (i < (1 << 20) + 3 * (1 << 18)) { src = wv; dst = wvb; off = (1 << 20) + 2 * (1 << 18); }
    else                                    { src = wo; dst = wob; off = (1 << 20) + 3 * (1 << 18); }
    int j = i - off;
    float4 v = reinterpret_cast<const float4*>(src)[j];
    bf16x4 o;
    o[0] = (__bf16)v.x; o[1] = (__bf16)v.y; o[2] = (__bf16)v.z; o[3] = (__bf16)v.w;
    reinterpret_cast<bf16x4*>(dst)[j] = o;
  } else {
    int i = (blk - 8192) * 256 + threadIdx.x;   // 0..65535 = S*32
    int s = i >> 5, f = i & 31;
    float freq = powf(10000.0f, -(float)(2 * f) / (float)HD_);
    float ang = (float)s * freq;
    tab[2 * i]     = cosf(ang);
    tab[2 * i + 1] = sinf(ang);
  }
}

// ---------------------------------------------------------------------------
// QKV GEMM: exact round-3 m97 structure (proven 53.6us): BK=32, 16KB LDS
// single buffer, __syncthreads + vmcnt(0) per iter (8 blocks/CU -> implicit
// cross-wave overlap hides staging; every explicit pipeline regressed).
// Epilogue: z=0/1 -> RoPE + head-split (Q pre-scaled by SCL2);
// z=2 -> V written DIRECTLY TRANSPOSED as Vt[bh][d][s] (bf16x4 8B stores),
// eliminating the separate vtrans kernel.
// ---------------------------------------------------------------------------
__global__ __launch_bounds__(256) void gemm_qkv(
    const __bf16* __restrict__ A, const __bf16* __restrict__ W0,
    const __bf16* __restrict__ W1, const __bf16* __restrict__ W2,
    __bf16* __restrict__ Cq, __bf16* __restrict__ Ck, __bf16* __restrict__ Cvt,
    const float* __restrict__ tab) {
  __shared__ __attribute__((aligned(16))) __bf16 As[128 * 32];
  __shared__ __attribute__((aligned(16))) __bf16 Bs[128 * 32];
  const int tid  = threadIdx.x;
  const int lane = tid & 63;
  const int wv   = tid >> 6;
  const int m0 = blockIdx.x * 128;
  const int n0 = blockIdx.y * 128;
  const int z  = blockIdx.z;
  const __bf16* W = (z == 0) ? W0 : (z == 1 ? W1 : W2);
  const int wm = (wv >> 1) * 64, wn = (wv & 1) * 64;
  const int arow = lane & 15;
  const int kgrp = (lane >> 4) * 8;

  f32x4 acc[4][4];
#pragma unroll
  for (int i = 0; i < 4; i++)
#pragma unroll
    for (int j = 0; j < 4; j++) acc[i][j] = f32x4{0.f, 0.f, 0.f, 0.f};

  for (int k0 = 0; k0 < 1024; k0 += 32) {
    __syncthreads();
#pragma unroll
    for (int j = 0; j < 2; ++j) {
      int c   = (wv * 2 + j) * 64 + lane;
      int row = c >> 2;
      int kc  = (c & 3) * 8;
      gload_lds16(A + (size_t)(m0 + row) * 1024 + k0 + kc,
                  As + (size_t)(wv * 2 + j) * 512);
      gload_lds16(W + (size_t)(n0 + row) * 1024 + k0 + kc,
                  Bs + (size_t)(wv * 2 + j) * 512);
    }
    asm volatile("s_waitcnt vmcnt(0)" ::: "memory");
    __syncthreads();
    bf16x8 af[4], bw[4];
#pragma unroll
    for (int i = 0; i < 4; i++)
      af[i] = *reinterpret_cast<const bf16x8*>(As + (wm + i * 16 + arow) * 32 + kgrp);
#pragma unroll
    for (int i = 0; i < 4; i++)
      bw[i] = *reinterpret_cast<const bf16x8*>(Bs + (wn + i * 16 + arow) * 32 + kgrp);
#pragma unroll
    for (int i = 0; i < 4; i++)
#pragma unroll
      for (int j = 0; j < 4; j++)
        acc[i][j] = __builtin_amdgcn_mfma_f32_16x16x32_bf16(af[i], bw[j], acc[i][j], 0, 0, 0);
  }

  // epilogue. C/D layout: col = lane&15 (n), row = (lane>>4)*4 + r (m)
  if (z == 2) {
    // V: write transposed Vt[bh][d][s]; r-loop = 4 consecutive srow -> bf16x4
#pragma unroll
    for (int i = 0; i < 4; i++) {
      int m = m0 + wm + i * 16 + (lane >> 4) * 4;   // +r, r=0..3 consecutive
      int bb = m >> 11, srow = m & (S_ - 1);        // constant across r
#pragma unroll
      for (int j = 0; j < 4; j++) {
        int n = n0 + wn + j * 16 + arow;
        int h = n >> 6, d = n & 63;
        bf16x4 o4;
#pragma unroll
        for (int r = 0; r < 4; r++) o4[r] = (__bf16)acc[i][j][r];
        *reinterpret_cast<bf16x4*>(
            Cvt + ((size_t)(bb * H_ + h) * HD_ + d) * S_ + srow) = o4;
      }
    }
  } else {
#pragma unroll
    for (int i = 0; i < 4; i++) {
#pragma unroll
      for (int j = 0; j < 4; j++) {
#pragma unroll
        for (int r = 0; r < 4; r++) {
          int m = m0 + wm + i * 16 + (lane >> 4) * 4 + r;
          int n = n0 + wn + j * 16 + arow;
          float v = acc[i][j][r];
          int bb = m >> 11, srow = m & (S_ - 1);
          int h = n >> 6, d = n & 63;
          size_t oidx = ((size_t)(bb * H_ + h) * S_ + srow) * HD_ + d;
          float other = __shfl_xor(v, 1, 64);   // n bit0 == lane bit0
          int fq = d >> 1;
          float2 cssn = *reinterpret_cast<const float2*>(tab + (srow * 32 + fq) * 2);
          float rv = (d & 1) ? (other * cssn.y + v * cssn.x)
                             : (v * cssn.x - other * cssn.y);
          if (z == 0) rv *= SCL2;   // pre-scale Q: logits in exp2 domain
          ((z == 0) ? Cq : Ck)[oidx] = (__bf16)rv;
        }
      }
    }
  }
}

// O-projection: C[m][n] = sum_k A[m][k] * W[n][k], fp32 out (m97 structure)
__global__ __launch_bounds__(256) void gemm_bt0(
    const __bf16* __restrict__ A, const __bf16* __restrict__ W0,
    float* __restrict__ Cf) {
  constexpr int BK = 32;
  __shared__ __attribute__((aligned(16))) __bf16 As[128 * BK];
  __shared__ __attribute__((aligned(16))) __bf16 Bs[128 * BK];
  const int tid  = threadIdx.x;
  const int lane = tid & 63;
  const int wv   = tid >> 6;
  const int m0 = blockIdx.x * 128;
  const int n0 = blockIdx.y * 128;
  const int wm = (wv >> 1) * 64, wn = (wv & 1) * 64;
  const int arow = lane & 15;
  const int kgrp = (lane >> 4) * 8;

  f32x4 acc[4][4];
#pragma unroll
  for (int i = 0; i < 4; i++)
#pragma unroll
    for (int j = 0; j < 4; j++) acc[i][j] = f32x4{0.f, 0.f, 0.f, 0.f};

  for (int k0 = 0; k0 < 1024; k0 += BK) {
    __syncthreads();
#pragma unroll
    for (int j = 0; j < 2; ++j) {
      int c   = (wv * 2 + j) * 64 + lane;
      int row = c >> 2;
      int kc  = (c & 3) * 8;
      gload_lds16(A + (size_t)(m0 + row) * 1024 + k0 + kc,
                  As + (size_t)(wv * 2 + j) * 512);
      gload_lds16(W0 + (size_t)(n0 + row) * 1024 + k0 + kc,
                  Bs + (size_t)(wv * 2 + j) * 512);
    }
    asm volatile("s_waitcnt vmcnt(0)" ::: "memory");
    __syncthreads();
    bf16x8 af[4], bw[4];
#pragma unroll
    for (int i = 0; i < 4; i++)
      af[i] = *reinterpret_cast<const bf16x8*>(As + (wm + i * 16 + arow) * BK + kgrp);
#pragma unroll
    for (int i = 0; i < 4; i++)
      bw[i] = *reinterpret_cast<const bf16x8*>(Bs + (wn + i * 16 + arow) * BK + kgrp);
#pragma unroll
    for (int i = 0; i < 4; i++)
#pragma unroll
      for (int j = 0; j < 4; j++)
        acc[i][j] = __builtin_amdgcn_mfma_f32_16x16x32_bf16(af[i], bw[j], acc[i][j], 0, 0, 0);
  }

#pragma unroll
  for (int i = 0; i < 4; i++)
#pragma unroll
    for (int j = 0; j < 4; j++)
#pragma unroll
      for (int r = 0; r < 4; r++) {
        int m = m0 + wm + i * 16 + (lane >> 4) * 4 + r;
        int n = n0 + wn + j * 16 + arow;
        Cf[(size_t)m * D_ + n] = acc[i][j][r];
      }
}

// Flash attention, causal. Grid: (bh=32, pr=16). Block: 4 waves x 16 q-rows,
// paired q-tiles (pr, 31-pr) => uniform 33 kv-iters per block.
// Swapped QK^T (P lane-local) + counted-vmcnt staging pipeline.
__global__ __launch_bounds__(256) void attn_kernel(
    const __bf16* __restrict__ Q, const __bf16* __restrict__ K,
    const __bf16* __restrict__ Vt, __bf16* __restrict__ O) {
  __shared__ __attribute__((aligned(16))) __bf16 Ks[2][64 * 64];
  __shared__ __attribute__((aligned(16))) __bf16 Vs[2][64 * 64];
  const int tid = threadIdx.x, lane = tid & 63, wv = tid >> 6;
  const int bh = blockIdx.x;   // stride-32 linear ids: all pr of one bh share an XCD
  const int pr = blockIdx.y;
  const int b = bh >> 4, h = bh & 15;
  const __bf16* Qb  = Q  + (size_t)bh * S_ * HD_;
  const __bf16* Kb  = K  + (size_t)bh * S_ * HD_;
  const __bf16* Vtb = Vt + (size_t)bh * HD_ * S_;
  const int arow = lane & 15, g = lane >> 4;

#define STAGE(K0, BK_, BV_)                                                   \
  do {                                                                        \
    _Pragma("unroll") for (int j = 0; j < 2; ++j) {                           \
      int G = (wv * 2 + j) * 64 + lane;                                       \
      int row = G >> 3, qq = G & 7;                                           \
      int qs = qq ^ (row & 7);                                                \
      int ctp = row >> 4, rw = row & 15;                                      \
      int kph = ((ctp >> 1) << 5) + ((rw >> 2) << 3) + ((ctp & 1) << 2)       \
                + (rw & 3);                                                   \
      gload_lds16(Kb + (size_t)((K0) + kph) * HD_ + qs * 8,                   \
                  (BK_) + (wv * 2 + j) * 512);                                \
      gload_lds16(Vtb + (size_t)row * S_ + (K0) + qs * 8,                     \
                  (BV_) + (wv * 2 + j) * 512);                                \
    }                                                                         \
  } while (0)

  for (int seg = 0; seg < 2; ++seg) {
    const int qt = (seg == 0) ? pr : 31 - pr;
    const int q0 = qt * 64;
    const int nkv = qt + 1;
    const int qw = q0 + wv * 16;
    const int qg = qw + arow;          // this thread's q-row

    bf16x8 aq[2];
#pragma unroll
    for (int j = 0; j < 2; j++)
      aq[j] = *reinterpret_cast<const bf16x8*>(
          Qb + (size_t)(qw + arow) * HD_ + j * 32 + g * 8);

    f32x4 po[4];
#pragma unroll
    for (int dt = 0; dt < 4; dt++) po[dt] = f32x4{0.f, 0.f, 0.f, 0.f};
    float mrow = -1e30f, lrow = 0.f;

    // prologue: stage tiles 0 and 1 (clamped); vmcnt(4) -> tile 0 landed
    STAGE(0, Ks[0], Vs[0]);
    {
      int t1 = (nkv > 1) ? 64 : 0;
      STAGE(t1, Ks[1], Vs[1]);
    }
    asm volatile("s_waitcnt vmcnt(4)" ::: "memory");
    __builtin_amdgcn_s_barrier();

    for (int kt = 0; kt < nkv; ++kt) {
      const int k0 = kt * 64;
      const int cur = kt & 1;
      const __bf16* Kc = Ks[cur];
      const __bf16* Vc = Vs[cur];

      // S^T = K Q^T : D[key][q], 8 MFMA
      f32x4 sc4[4];
      __builtin_amdgcn_s_setprio(1);
#pragma unroll
      for (int ct = 0; ct < 4; ct++) {
        sc4[ct] = f32x4{0.f, 0.f, 0.f, 0.f};
        int L = ct * 16 + arow;
#pragma unroll
        for (int j2 = 0; j2 < 2; j2++) {
          int byt = (L * 128 + j2 * 64 + g * 16) ^ ((L & 7) << 4);
          bf16x8 kb = *reinterpret_cast<const bf16x8*>((const char*)Kc + byt);
          sc4[ct] = __builtin_amdgcn_mfma_f32_16x16x32_bf16(kb, aq[j2], sc4[ct], 0, 0, 0);
        }
      }
      __builtin_amdgcn_s_setprio(0);

      // causal mask (diagonal tile only)
      const bool full = (kt < nkv - 1);
      if (!full) {
#pragma unroll
        for (int ct = 0; ct < 4; ct++) {
          int kb0 = k0 + ((ct >> 1) << 5) + ((ct & 1) << 2) + g * 8;
#pragma unroll
          for (int r = 0; r < 4; r++)
            if (kb0 + r > qg) sc4[ct][r] = -1e30f;
        }
      }

      // in-register online softmax (one q-row per lane)
      float mx = -1e30f;
#pragma unroll
      for (int ct = 0; ct < 4; ct++)
#pragma unroll
        for (int r = 0; r < 4; r++) mx = fmaxf(mx, sc4[ct][r]);
      mx = fmaxf(mx, __shfl_xor(mx, 16, 64));
      mx = fmaxf(mx, __shfl_xor(mx, 32, 64));

      bool noskip = !__all(mx <= mrow + 11.0f);
      if (noskip) {
        float mnew = fmaxf(mrow, mx);
        float corr = fexp2(mrow - mnew);
        mrow = mnew;
        lrow *= corr;
#pragma unroll
        for (int dt = 0; dt < 4; dt++)
#pragma unroll
          for (int r = 0; r < 4; r++) po[dt][r] *= corr;
      }

      float rs = 0.f;
      float pv[4][4];
#pragma unroll
      for (int ct = 0; ct < 4; ct++)
#pragma unroll
        for (int r = 0; r < 4; r++) {
          float e = fexp2(sc4[ct][r] - mrow);
          pv[ct][r] = e;
          rs += e;
        }
      rs += __shfl_xor(rs, 16, 64);
      rs += __shfl_xor(rs, 32, 64);
      lrow += rs;

      // pack P: pb[j2] holds physical keys j2*32 + g*8 .. +7 (lane-local)
      bf16x8 pb[2];
#pragma unroll
      for (int j2 = 0; j2 < 2; j2++) {
#pragma unroll
        for (int r = 0; r < 4; r++) {
          pb[j2][r]     = (__bf16)pv[2 * j2][r];
          pb[j2][4 + r] = (__bf16)pv[2 * j2 + 1][r];
        }
      }

      // O^T += V^T P^T : po[dt] = D[d][q], d = dt*16 + g*4 + r, q = arow
      __builtin_amdgcn_s_setprio(1);
#pragma unroll
      for (int dt = 0; dt < 4; dt++) {
        int d = dt * 16 + arow;
#pragma unroll
        for (int j2 = 0; j2 < 2; j2++) {
          int byv = (d * 128 + j2 * 64 + g * 16) ^ ((d & 7) << 4);
          bf16x8 vb = *reinterpret_cast<const bf16x8*>((const char*)Vc + byv);
          po[dt] = __builtin_amdgcn_mfma_f32_16x16x32_bf16(vb, pb[j2], po[dt], 0, 0, 0);
        }
      }
      __builtin_amdgcn_s_setprio(0);

      // pipeline tail: all waves done reading buf[cur], then stage kt+2
      __builtin_amdgcn_s_barrier();
      if (kt < nkv - 1) {
        int nx = kt + 2;
        if (nx > nkv - 1) nx = nkv - 1;     // clamp: uniform 4-load count
        STAGE(nx * 64, Ks[cur], Vs[cur]);   // overwrite retired buffer
        asm volatile("s_waitcnt vmcnt(4)" ::: "memory");  // tile kt+1 landed
      } else {
        asm volatile("s_waitcnt vmcnt(0)" ::: "memory");  // drain for next seg
      }
      __builtin_amdgcn_s_barrier();
    }

    float inv = __builtin_amdgcn_rcpf(lrow);
#pragma unroll
    for (int dt = 0; dt < 4; dt++) {
      bf16x4 o4;
#pragma unroll
      for (int r = 0; r < 4; r++) o4[r] = (__bf16)(po[dt][r] * inv);
      *reinterpret_cast<bf16x4*>(
          O + (size_t)(b * S_ + qg) * D_ + h * HD_ + dt * 16 + g * 4) = o4;
    }
  }
#undef STAGE
}

extern "C" void kernel_launch(void* const* d_in, const int* in_sizes, int n_in,
                              void* d_out, int out_size, void* d_ws, size_t ws_size,
                              hipStream_t stream) {
  const float* x  = (const float*)d_in[0];
  const float* wq = (const float*)d_in[1];
  const float* wk = (const float*)d_in[2];
  const float* wv = (const float*)d_in[3];
  const float* wo = (const float*)d_in[4];
  float* out = (float*)d_out;

  char* w = (char*)d_ws;
  __bf16* xb  = (__bf16*)(w);                    // 8 MB
  __bf16* wqb = (__bf16*)(w + (8u  << 20));      // 2 MB each
  __bf16* wkb = (__bf16*)(w + (10u << 20));
  __bf16* wvb = (__bf16*)(w + (12u << 20));
  __bf16* wob = (__bf16*)(w + (14u << 20));
  __bf16* qws = (__bf16*)(w + (16u << 20));      // 8 MB each
  __bf16* kws = (__bf16*)(w + (24u << 20));
  __bf16* vtw = (__bf16*)(w + (32u << 20));      // V, stored TRANSPOSED [bh][d][s]
  __bf16* aws = (__bf16*)(w + (40u << 20));      // attn out, [token][feature]
  float*  tab = (float*)(w + (48u << 20));       // 512 KB rope table

  cvt_all_kernel<<<8448, 256, 0, stream>>>(x, wq, wk, wv, wo,
                                           xb, wqb, wkb, wvb, wob, tab);
  gemm_qkv<<<dim3(32, 8, 3), 256, 0, stream>>>(xb, wqb, wkb, wvb,
                                               qws, kws, vtw, tab);
  attn_kernel<<<dim3(2 * H_, S_ / 128), 256, 0, stream>>>(qws, kws, vtw, aws);
  gemm_bt0<<<dim3(M_ / 128, D_ / 128), 256, 0, stream>>>(aws, wob, out);
}

// Round 9
// 120.018 us; speedup vs baseline: 1.2197x; 1.0478x over previous
//
#include <hip/hip_runtime.h>
#include <hip/hip_bf16.h>
#include <stdint.h>

typedef __attribute__((ext_vector_type(4))) float f32x4;
typedef __attribute__((ext_vector_type(8))) __bf16 bf16x8;
typedef __attribute__((ext_vector_type(4))) __bf16 bf16x4;

#define DEVI __device__ __forceinline__

static constexpr int S_  = 2048;
static constexpr int D_  = 1024;
static constexpr int H_  = 16;
static constexpr int HD_ = 64;
static constexpr int M_  = 2 * S_;   // B*S = 4096 token rows
static constexpr float SCL2 = 0.18033688f;  // 0.125 * log2(e)

DEVI void gload_lds16(const void* gsrc, void* ldst) {
  __builtin_amdgcn_global_load_lds(
      (__attribute__((address_space(1))) void*)(void*)gsrc,
      (__attribute__((address_space(3))) void*)ldst, 16, 0, 0);
}

DEVI float fexp2(float x) {
  float r;
  asm("v_exp_f32 %0, %1" : "=v"(r) : "v"(x));
  return r;
}

// One fused conversion kernel: x + 4 weights fp32->bf16, plus RoPE table.
__global__ __launch_bounds__(256) void cvt_all_kernel(
    const float* __restrict__ x, const float* __restrict__ wq,
    const float* __restrict__ wk, const float* __restrict__ wv,
    const float* __restrict__ wo,
    __bf16* __restrict__ xb, __bf16* __restrict__ wqb,
    __bf16* __restrict__ wkb, __bf16* __restrict__ wvb,
    __bf16* __restrict__ wob, float* __restrict__ tab) {
  int blk = blockIdx.x;
  if (blk < 8192) {
    int i = blk * 256 + threadIdx.x;     // float4 index
    const float* src; __bf16* dst; int off;
    if (i < (1 << 20))                      { src = x;  dst = xb;  off = 0; }
    else if (i < (1 << 20) + (1 << 18))     { src = wq; dst = wqb; off = (1 << 20); }
    else if (i < (1 << 20) + 2 * (1 << 18)) { src = wk; dst = wkb; off = (1 << 20) + (1 << 18); }
    else if (i < (1 << 20) + 3 * (1 << 18)) { src = wv; dst = wvb; off = (1 << 20) + 2 * (1 << 18); }
    else                                    { src = wo; dst = wob; off = (1 << 20) + 3 * (1 << 18); }
    int j = i - off;
    float4 v = reinterpret_cast<const float4*>(src)[j];
    bf16x4 o;
    o[0] = (__bf16)v.x; o[1] = (__bf16)v.y; o[2] = (__bf16)v.z; o[3] = (__bf16)v.w;
    reinterpret_cast<bf16x4*>(dst)[j] = o;
  } else {
    int i = (blk - 8192) * 256 + threadIdx.x;   // 0..65535 = S*32
    int s = i >> 5, f = i & 31;
    float freq = powf(10000.0f, -(float)(2 * f) / (float)HD_);
    float ang = (float)s * freq;
    tab[2 * i]     = cosf(ang);
    tab[2 * i + 1] = sinf(ang);
  }
}

// ---------------------------------------------------------------------------
// QKV GEMM: m97 128x128 BK=32 single-buffer structure (proven; every explicit
// pipeline regressed -- implicit cross-block wave overlap wins).
// z=0/1 -> RoPE + head-split (Q pre-scaled by SCL2);
// z=2 -> V written DIRECTLY TRANSPOSED as Vt[bh][d][s] (bf16x4 stores).
// ---------------------------------------------------------------------------
__global__ __launch_bounds__(256) void gemm_qkv(
    const __bf16* __restrict__ A, const __bf16* __restrict__ W0,
    const __bf16* __restrict__ W1, const __bf16* __restrict__ W2,
    __bf16* __restrict__ Cq, __bf16* __restrict__ Ck, __bf16* __restrict__ Cvt,
    const float* __restrict__ tab) {
  __shared__ __attribute__((aligned(16))) __bf16 As[128 * 32];
  __shared__ __attribute__((aligned(16))) __bf16 Bs[128 * 32];
  const int tid  = threadIdx.x;
  const int lane = tid & 63;
  const int wv   = tid >> 6;
  const int m0 = blockIdx.x * 128;
  const int n0 = blockIdx.y * 128;
  const int z  = blockIdx.z;
  const __bf16* W = (z == 0) ? W0 : (z == 1 ? W1 : W2);
  const int wm = (wv >> 1) * 64, wn = (wv & 1) * 64;
  const int arow = lane & 15;
  const int kgrp = (lane >> 4) * 8;

  f32x4 acc[4][4];
#pragma unroll
  for (int i = 0; i < 4; i++)
#pragma unroll
    for (int j = 0; j < 4; j++) acc[i][j] = f32x4{0.f, 0.f, 0.f, 0.f};

  for (int k0 = 0; k0 < 1024; k0 += 32) {
    __syncthreads();
#pragma unroll
    for (int j = 0; j < 2; ++j) {
      int c   = (wv * 2 + j) * 64 + lane;
      int row = c >> 2;
      int kc  = (c & 3) * 8;
      gload_lds16(A + (size_t)(m0 + row) * 1024 + k0 + kc,
                  As + (size_t)(wv * 2 + j) * 512);
      gload_lds16(W + (size_t)(n0 + row) * 1024 + k0 + kc,
                  Bs + (size_t)(wv * 2 + j) * 512);
    }
    asm volatile("s_waitcnt vmcnt(0)" ::: "memory");
    __syncthreads();
    bf16x8 af[4], bw[4];
#pragma unroll
    for (int i = 0; i < 4; i++)
      af[i] = *reinterpret_cast<const bf16x8*>(As + (wm + i * 16 + arow) * 32 + kgrp);
#pragma unroll
    for (int i = 0; i < 4; i++)
      bw[i] = *reinterpret_cast<const bf16x8*>(Bs + (wn + i * 16 + arow) * 32 + kgrp);
#pragma unroll
    for (int i = 0; i < 4; i++)
#pragma unroll
      for (int j = 0; j < 4; j++)
        acc[i][j] = __builtin_amdgcn_mfma_f32_16x16x32_bf16(af[i], bw[j], acc[i][j], 0, 0, 0);
  }

  // epilogue. C/D layout: col = lane&15 (n), row = (lane>>4)*4 + r (m)
  if (z == 2) {
#pragma unroll
    for (int i = 0; i < 4; i++) {
      int m = m0 + wm + i * 16 + (lane >> 4) * 4;
      int bb = m >> 11, srow = m & (S_ - 1);
#pragma unroll
      for (int j = 0; j < 4; j++) {
        int n = n0 + wn + j * 16 + arow;
        int h = n >> 6, d = n & 63;
        bf16x4 o4;
#pragma unroll
        for (int r = 0; r < 4; r++) o4[r] = (__bf16)acc[i][j][r];
        *reinterpret_cast<bf16x4*>(
            Cvt + ((size_t)(bb * H_ + h) * HD_ + d) * S_ + srow) = o4;
      }
    }
  } else {
#pragma unroll
    for (int i = 0; i < 4; i++) {
#pragma unroll
      for (int j = 0; j < 4; j++) {
#pragma unroll
        for (int r = 0; r < 4; r++) {
          int m = m0 + wm + i * 16 + (lane >> 4) * 4 + r;
          int n = n0 + wn + j * 16 + arow;
          float v = acc[i][j][r];
          int bb = m >> 11, srow = m & (S_ - 1);
          int h = n >> 6, d = n & 63;
          size_t oidx = ((size_t)(bb * H_ + h) * S_ + srow) * HD_ + d;
          float other = __shfl_xor(v, 1, 64);   // n bit0 == lane bit0
          int fq = d >> 1;
          float2 cssn = *reinterpret_cast<const float2*>(tab + (srow * 32 + fq) * 2);
          float rv = (d & 1) ? (other * cssn.y + v * cssn.x)
                             : (v * cssn.x - other * cssn.y);
          if (z == 0) rv *= SCL2;   // pre-scale Q: logits in exp2 domain
          ((z == 0) ? Cq : Ck)[oidx] = (__bf16)rv;
        }
      }
    }
  }
}

// O-projection: C[m][n] = sum_k A[m][k] * W[n][k], fp32 out (m97 structure)
__global__ __launch_bounds__(256) void gemm_bt0(
    const __bf16* __restrict__ A, const __bf16* __restrict__ W0,
    float* __restrict__ Cf) {
  constexpr int BK = 32;
  __shared__ __attribute__((aligned(16))) __bf16 As[128 * BK];
  __shared__ __attribute__((aligned(16))) __bf16 Bs[128 * BK];
  const int tid  = threadIdx.x;
  const int lane = tid & 63;
  const int wv   = tid >> 6;
  const int m0 = blockIdx.x * 128;
  const int n0 = blockIdx.y * 128;
  const int wm = (wv >> 1) * 64, wn = (wv & 1) * 64;
  const int arow = lane & 15;
  const int kgrp = (lane >> 4) * 8;

  f32x4 acc[4][4];
#pragma unroll
  for (int i = 0; i < 4; i++)
#pragma unroll
    for (int j = 0; j < 4; j++) acc[i][j] = f32x4{0.f, 0.f, 0.f, 0.f};

  for (int k0 = 0; k0 < 1024; k0 += BK) {
    __syncthreads();
#pragma unroll
    for (int j = 0; j < 2; ++j) {
      int c   = (wv * 2 + j) * 64 + lane;
      int row = c >> 2;
      int kc  = (c & 3) * 8;
      gload_lds16(A + (size_t)(m0 + row) * 1024 + k0 + kc,
                  As + (size_t)(wv * 2 + j) * 512);
      gload_lds16(W0 + (size_t)(n0 + row) * 1024 + k0 + kc,
                  Bs + (size_t)(wv * 2 + j) * 512);
    }
    asm volatile("s_waitcnt vmcnt(0)" ::: "memory");
    __syncthreads();
    bf16x8 af[4], bw[4];
#pragma unroll
    for (int i = 0; i < 4; i++)
      af[i] = *reinterpret_cast<const bf16x8*>(As + (wm + i * 16 + arow) * BK + kgrp);
#pragma unroll
    for (int i = 0; i < 4; i++)
      bw[i] = *reinterpret_cast<const bf16x8*>(Bs + (wn + i * 16 + arow) * BK + kgrp);
#pragma unroll
    for (int i = 0; i < 4; i++)
#pragma unroll
      for (int j = 0; j < 4; j++)
        acc[i][j] = __builtin_amdgcn_mfma_f32_16x16x32_bf16(af[i], bw[j], acc[i][j], 0, 0, 0);
  }

#pragma unroll
  for (int i = 0; i < 4; i++)
#pragma unroll
    for (int j = 0; j < 4; j++)
#pragma unroll
      for (int r = 0; r < 4; r++) {
        int m = m0 + wm + i * 16 + (lane >> 4) * 4 + r;
        int n = n0 + wn + j * 16 + arow;
        Cf[(size_t)m * D_ + n] = acc[i][j][r];
      }
}

// ---------------------------------------------------------------------------
// Flash attention, causal. Grid: (bh=32, pr=16). Block: 4 waves x 16 q-rows,
// paired q-tiles (pr, 31-pr) => uniform 17 kv-iters (KVBLK=128 keys/iter:
// half the barriers/waits/softmax-rescale chains of the 64-key version).
// Swapped QK^T (P lane-local). K LDS [128 key][64 d] with key-permutation
// (incl. 64-offset bit) so each lane's 32 P-values are exactly the 4 PV
// B-fragments; V LDS [64 d][128 key], row stride 256B, (d&7)<<4 XOR swizzle.
// Staging: linear-dest global_load_lds + inverse-swizzled source; counted
// vmcnt(8) double-buffer pipeline (proven pattern).
// ---------------------------------------------------------------------------
__global__ __launch_bounds__(256, 2) void attn_kernel(
    const __bf16* __restrict__ Q, const __bf16* __restrict__ K,
    const __bf16* __restrict__ Vt, __bf16* __restrict__ O) {
  __shared__ __attribute__((aligned(16))) __bf16 Ks[2][128 * 64];
  __shared__ __attribute__((aligned(16))) __bf16 Vs[2][64 * 128];
  const int tid = threadIdx.x, lane = tid & 63, wv = tid >> 6;
  const int bh = blockIdx.x;   // linear id stride 32 => all pr of a bh share an XCD
  const int pr = blockIdx.y;
  const int b = bh >> 4, h = bh & 15;
  const __bf16* Qb  = Q  + (size_t)bh * S_ * HD_;
  const __bf16* Kb  = K  + (size_t)bh * S_ * HD_;
  const __bf16* Vtb = Vt + (size_t)bh * HD_ * S_;
  const int arow = lane & 15, g = lane >> 4;

  // 8 gload_lds16 per thread per 128-key tile (4 K-chunks + 4 V-chunks)
#define STAGE(K0, BK_, BV_)                                                   \
  do {                                                                        \
    _Pragma("unroll") for (int j = 0; j < 4; ++j) {                           \
      int c = (wv * 4 + j) * 64 + lane;          /* chunk 0..1023 */          \
      int rowk = c >> 3, qqk = c & 7;                                         \
      int qsk = qqk ^ (rowk & 7);                                             \
      int ctp = rowk >> 4, rw = rowk & 15;                                    \
      int kph = ((ctp & 4) << 4) + ((ctp & 2) << 4) + ((ctp & 1) << 2)        \
                + ((rw >> 2) << 3) + (rw & 3);                                \
      gload_lds16(Kb + (size_t)((K0) + kph) * HD_ + qsk * 8,                  \
                  (BK_) + (size_t)(wv * 4 + j) * 512);                        \
      int rowv = c >> 4, qqv = c & 15;                                        \
      int qsv = qqv ^ (rowv & 7);                                             \
      gload_lds16(Vtb + (size_t)rowv * S_ + (K0) + qsv * 8,                   \
                  (BV_) + (size_t)(wv * 4 + j) * 512);                        \
    }                                                                         \
  } while (0)

  for (int seg = 0; seg < 2; ++seg) {
    const int qt = (seg == 0) ? pr : 31 - pr;   // 64-row q-tile index
    const int q0 = qt * 64;
    const int nkv = (qt >> 1) + 1;              // 128-key tiles
    const int qw = q0 + wv * 16;
    const int qg = qw + arow;                   // this thread's q-row

    bf16x8 aq[2];
#pragma unroll
    for (int j = 0; j < 2; j++)
      aq[j] = *reinterpret_cast<const bf16x8*>(
          Qb + (size_t)(qw + arow) * HD_ + j * 32 + g * 8);

    f32x4 po[4];
#pragma unroll
    for (int dt = 0; dt < 4; dt++) po[dt] = f32x4{0.f, 0.f, 0.f, 0.f};
    float mrow = -1e30f, lrow = 0.f;

    // prologue: stage tiles 0 and 1 (clamped); vmcnt(8) -> tile 0 landed
    STAGE(0, Ks[0], Vs[0]);
    {
      int t1 = (nkv > 1) ? 128 : 0;
      STAGE(t1, Ks[1], Vs[1]);
    }
    asm volatile("s_waitcnt vmcnt(8)" ::: "memory");
    __builtin_amdgcn_s_barrier();

    for (int kt = 0; kt < nkv; ++kt) {
      const int k0 = kt * 128;
      const int cur = kt & 1;
      const __bf16* Kc = Ks[cur];
      const __bf16* Vc = Vs[cur];

      // S^T = K Q^T : D[key][q], 16 MFMA over 128 keys
      f32x4 sc4[8];
      __builtin_amdgcn_s_setprio(1);
#pragma unroll
      for (int ct = 0; ct < 8; ct++) {
        sc4[ct] = f32x4{0.f, 0.f, 0.f, 0.f};
        int L = ct * 16 + arow;
#pragma unroll
        for (int j2 = 0; j2 < 2; j2++) {
          int byt = (L * 128 + j2 * 64 + g * 16) ^ ((L & 7) << 4);
          bf16x8 kb = *reinterpret_cast<const bf16x8*>((const char*)Kc + byt);
          sc4[ct] = __builtin_amdgcn_mfma_f32_16x16x32_bf16(kb, aq[j2], sc4[ct], 0, 0, 0);
        }
      }
      __builtin_amdgcn_s_setprio(0);

      // causal mask (last tile only). physical key of sc4[ct][r]:
      // k0 + (ct&4)*16 + (ct&2)*16 + (ct&1)*4 + g*8 + r
      if (kt == nkv - 1) {
#pragma unroll
        for (int ct = 0; ct < 8; ct++) {
          int kb0 = k0 + ((ct & 4) << 4) + ((ct & 2) << 4) + ((ct & 1) << 2) + g * 8;
#pragma unroll
          for (int r = 0; r < 4; r++)
            if (kb0 + r > qg) sc4[ct][r] = -1e30f;
        }
      }

      // in-register online softmax (one q-row per lane, 32 values)
      float mx = -1e30f;
#pragma unroll
      for (int ct = 0; ct < 8; ct++)
#pragma unroll
        for (int r = 0; r < 4; r++) mx = fmaxf(mx, sc4[ct][r]);
      mx = fmaxf(mx, __shfl_xor(mx, 16, 64));
      mx = fmaxf(mx, __shfl_xor(mx, 32, 64));

      bool noskip = !__all(mx <= mrow + 11.0f);
      if (noskip) {
        float mnew = fmaxf(mrow, mx);
        float corr = fexp2(mrow - mnew);
        mrow = mnew;
        lrow *= corr;
#pragma unroll
        for (int dt = 0; dt < 4; dt++)
#pragma unroll
          for (int r = 0; r < 4; r++) po[dt][r] *= corr;
      }

      float rs = 0.f;
#pragma unroll
      for (int ct = 0; ct < 8; ct++)
#pragma unroll
        for (int r = 0; r < 4; r++) {
          float e = fexp2(sc4[ct][r] - mrow);
          sc4[ct][r] = e;            // overwrite in place (VGPR economy)
          rs += e;
        }
      rs += __shfl_xor(rs, 16, 64);
      rs += __shfl_xor(rs, 32, 64);
      lrow += rs;

      // pack P: pb[jj] holds physical keys jj*32 + g*8 .. +7 (lane-local)
      bf16x8 pb[4];
#pragma unroll
      for (int h2 = 0; h2 < 2; h2++)
#pragma unroll
        for (int j2 = 0; j2 < 2; j2++) {
#pragma unroll
          for (int r = 0; r < 4; r++) {
            pb[h2 * 2 + j2][r]     = (__bf16)sc4[h2 * 4 + 2 * j2][r];
            pb[h2 * 2 + j2][4 + r] = (__bf16)sc4[h2 * 4 + 2 * j2 + 1][r];
          }
        }

      // O^T += V^T P^T : po[dt] = D[d][q], d = dt*16 + g*4 + r, q = arow
      __builtin_amdgcn_s_setprio(1);
#pragma unroll
      for (int dt = 0; dt < 4; dt++) {
        int d = dt * 16 + arow;
#pragma unroll
        for (int jj = 0; jj < 4; jj++) {
          int byv = (d * 256 + jj * 64 + g * 16) ^ ((d & 7) << 4);
          bf16x8 vb = *reinterpret_cast<const bf16x8*>((const char*)Vc + byv);
          po[dt] = __builtin_amdgcn_mfma_f32_16x16x32_bf16(vb, pb[jj], po[dt], 0, 0, 0);
        }
      }
      __builtin_amdgcn_s_setprio(0);

      // pipeline tail: all waves done reading buf[cur], then stage kt+2
      __builtin_amdgcn_s_barrier();
      if (kt < nkv - 1) {
        int nx = kt + 2;
        if (nx > nkv - 1) nx = nkv - 1;       // clamp: uniform 8-load count
        STAGE(nx * 128, Ks[cur], Vs[cur]);    // overwrite retired buffer
        asm volatile("s_waitcnt vmcnt(8)" ::: "memory");  // tile kt+1 landed
      } else {
        asm volatile("s_waitcnt vmcnt(0)" ::: "memory");  // drain for next seg
      }
      __builtin_amdgcn_s_barrier();
    }

    float inv = __builtin_amdgcn_rcpf(lrow);
#pragma unroll
    for (int dt = 0; dt < 4; dt++) {
      bf16x4 o4;
#pragma unroll
      for (int r = 0; r < 4; r++) o4[r] = (__bf16)(po[dt][r] * inv);
      *reinterpret_cast<bf16x4*>(
          O + (size_t)(b * S_ + qg) * D_ + h * HD_ + dt * 16 + g * 4) = o4;
    }
  }
#undef STAGE
}

extern "C" void kernel_launch(void* const* d_in, const int* in_sizes, int n_in,
                              void* d_out, int out_size, void* d_ws, size_t ws_size,
                              hipStream_t stream) {
  const float* x  = (const float*)d_in[0];
  const float* wq = (const float*)d_in[1];
  const float* wk = (const float*)d_in[2];
  const float* wv = (const float*)d_in[3];
  const float* wo = (const float*)d_in[4];
  float* out = (float*)d_out;

  char* w = (char*)d_ws;
  __bf16* xb  = (__bf16*)(w);                    // 8 MB
  __bf16* wqb = (__bf16*)(w + (8u  << 20));      // 2 MB each
  __bf16* wkb = (__bf16*)(w + (10u << 20));
  __bf16* wvb = (__bf16*)(w + (12u << 20));
  __bf16* wob = (__bf16*)(w + (14u << 20));
  __bf16* qws = (__bf16*)(w + (16u << 20));      // 8 MB each
  __bf16* kws = (__bf16*)(w + (24u << 20));
  __bf16* vtw = (__bf16*)(w + (32u << 20));      // V, stored TRANSPOSED [bh][d][s]
  __bf16* aws = (__bf16*)(w + (40u << 20));      // attn out, [token][feature]
  float*  tab = (float*)(w + (48u << 20));       // 512 KB rope table

  cvt_all_kernel<<<8448, 256, 0, stream>>>(x, wq, wk, wv, wo,
                                           xb, wqb, wkb, wvb, wob, tab);
  gemm_qkv<<<dim3(32, 8, 3), 256, 0, stream>>>(xb, wqb, wkb, wvb,
                                               qws, kws, vtw, tab);
  attn_kernel<<<dim3(2 * H_, S_ / 128), 256, 0, stream>>>(qws, kws, vtw, aws);
  gemm_bt0<<<dim3(M_ / 128, D_ / 128), 256, 0, stream>>>(aws, wob, out);
}

// Round 10
// 119.210 us; speedup vs baseline: 1.2280x; 1.0068x over previous
//
#include <hip/hip_runtime.h>
#include <hip/hip_bf16.h>
#include <stdint.h>

typedef __attribute__((ext_vector_type(4))) float f32x4;
typedef __attribute__((ext_vector_type(8))) __bf16 bf16x8;
typedef __attribute__((ext_vector_type(4))) __bf16 bf16x4;

#define DEVI __device__ __forceinline__

static constexpr int S_  = 2048;
static constexpr int D_  = 1024;
static constexpr int H_  = 16;
static constexpr int HD_ = 64;
static constexpr int M_  = 2 * S_;   // B*S = 4096 token rows
static constexpr float SCL2 = 0.18033688f;  // 0.125 * log2(e)

DEVI void gload_lds16(const void* gsrc, void* ldst) {
  __builtin_amdgcn_global_load_lds(
      (__attribute__((address_space(1))) void*)(void*)gsrc,
      (__attribute__((address_space(3))) void*)ldst, 16, 0, 0);
}

DEVI float fexp2(float x) {
  float r;
  asm("v_exp_f32 %0, %1" : "=v"(r) : "v"(x));
  return r;
}

// One fused conversion kernel: x + 4 weights fp32->bf16, plus RoPE table.
__global__ __launch_bounds__(256) void cvt_all_kernel(
    const float* __restrict__ x, const float* __restrict__ wq,
    const float* __restrict__ wk, const float* __restrict__ wv,
    const float* __restrict__ wo,
    __bf16* __restrict__ xb, __bf16* __restrict__ wqb,
    __bf16* __restrict__ wkb, __bf16* __restrict__ wvb,
    __bf16* __restrict__ wob, float* __restrict__ tab) {
  int blk = blockIdx.x;
  if (blk < 8192) {
    int i = blk * 256 + threadIdx.x;     // float4 index
    const float* src; __bf16* dst; int off;
    if (i < (1 << 20))                      { src = x;  dst = xb;  off = 0; }
    else if (i < (1 << 20) + (1 << 18))     { src = wq; dst = wqb; off = (1 << 20); }
    else if (i < (1 << 20) + 2 * (1 << 18)) { src = wk; dst = wkb; off = (1 << 20) + (1 << 18); }
    else if (i < (1 << 20) + 3 * (1 << 18)) { src = wv; dst = wvb; off = (1 << 20) + 2 * (1 << 18); }
    else                                    { src = wo; dst = wob; off = (1 << 20) + 3 * (1 << 18); }
    int j = i - off;
    float4 v = reinterpret_cast<const float4*>(src)[j];
    bf16x4 o;
    o[0] = (__bf16)v.x; o[1] = (__bf16)v.y; o[2] = (__bf16)v.z; o[3] = (__bf16)v.w;
    reinterpret_cast<bf16x4*>(dst)[j] = o;
  } else {
    int i = (blk - 8192) * 256 + threadIdx.x;   // 0..65535 = S*32
    int s = i >> 5, f = i & 31;
    float freq = powf(10000.0f, -(float)(2 * f) / (float)HD_);
    float ang = (float)s * freq;
    tab[2 * i]     = cosf(ang);
    tab[2 * i + 1] = sinf(ang);
  }
}

// ---------------------------------------------------------------------------
// QKV GEMM: m97 128x128 structure, BK=64 realized as TWO back-to-back linear
// BK=32 sub-tiles (identical staging/read pattern to the proven r8 kernel,
// zero new address math) -> one vmcnt(0) drain + one barrier pair per 64
// K-columns instead of two. 16 K-iters. LDS 32KB (>=3 blocks/CU).
// z=0/1 -> RoPE + head-split (Q pre-scaled by SCL2);
// z=2 -> V written DIRECTLY TRANSPOSED as Vt[bh][d][s].
// ---------------------------------------------------------------------------
__global__ __launch_bounds__(256) void gemm_qkv(
    const __bf16* __restrict__ A, const __bf16* __restrict__ W0,
    const __bf16* __restrict__ W1, const __bf16* __restrict__ W2,
    __bf16* __restrict__ Cq, __bf16* __restrict__ Ck, __bf16* __restrict__ Cvt,
    const float* __restrict__ tab) {
  __shared__ __attribute__((aligned(16))) __bf16 As[2][128 * 32];
  __shared__ __attribute__((aligned(16))) __bf16 Bs[2][128 * 32];
  const int tid  = threadIdx.x;
  const int lane = tid & 63;
  const int wv   = tid >> 6;
  const int m0 = blockIdx.x * 128;
  const int n0 = blockIdx.y * 128;
  const int z  = blockIdx.z;
  const __bf16* W = (z == 0) ? W0 : (z == 1 ? W1 : W2);
  const int wm = (wv >> 1) * 64, wn = (wv & 1) * 64;
  const int arow = lane & 15;
  const int kgrp = (lane >> 4) * 8;

  f32x4 acc[4][4];
#pragma unroll
  for (int i = 0; i < 4; i++)
#pragma unroll
    for (int j = 0; j < 4; j++) acc[i][j] = f32x4{0.f, 0.f, 0.f, 0.f};

  for (int k0 = 0; k0 < 1024; k0 += 64) {
    __syncthreads();
#pragma unroll
    for (int hh = 0; hh < 2; ++hh) {
#pragma unroll
      for (int j = 0; j < 2; ++j) {
        int c   = (wv * 2 + j) * 64 + lane;
        int row = c >> 2;
        int kc  = (c & 3) * 8;
        gload_lds16(A + (size_t)(m0 + row) * 1024 + k0 + hh * 32 + kc,
                    As[hh] + (size_t)(wv * 2 + j) * 512);
        gload_lds16(W + (size_t)(n0 + row) * 1024 + k0 + hh * 32 + kc,
                    Bs[hh] + (size_t)(wv * 2 + j) * 512);
      }
    }
    asm volatile("s_waitcnt vmcnt(0)" ::: "memory");
    __syncthreads();
#pragma unroll
    for (int hh = 0; hh < 2; ++hh) {
      bf16x8 af[4], bw[4];
#pragma unroll
      for (int i = 0; i < 4; i++)
        af[i] = *reinterpret_cast<const bf16x8*>(As[hh] + (wm + i * 16 + arow) * 32 + kgrp);
#pragma unroll
      for (int i = 0; i < 4; i++)
        bw[i] = *reinterpret_cast<const bf16x8*>(Bs[hh] + (wn + i * 16 + arow) * 32 + kgrp);
#pragma unroll
      for (int i = 0; i < 4; i++)
#pragma unroll
        for (int j = 0; j < 4; j++)
          acc[i][j] = __builtin_amdgcn_mfma_f32_16x16x32_bf16(af[i], bw[j], acc[i][j], 0, 0, 0);
    }
  }

  // epilogue. C/D layout: col = lane&15 (n), row = (lane>>4)*4 + r (m)
  if (z == 2) {
#pragma unroll
    for (int i = 0; i < 4; i++) {
      int m = m0 + wm + i * 16 + (lane >> 4) * 4;
      int bb = m >> 11, srow = m & (S_ - 1);
#pragma unroll
      for (int j = 0; j < 4; j++) {
        int n = n0 + wn + j * 16 + arow;
        int h = n >> 6, d = n & 63;
        bf16x4 o4;
#pragma unroll
        for (int r = 0; r < 4; r++) o4[r] = (__bf16)acc[i][j][r];
        *reinterpret_cast<bf16x4*>(
            Cvt + ((size_t)(bb * H_ + h) * HD_ + d) * S_ + srow) = o4;
      }
    }
  } else {
#pragma unroll
    for (int i = 0; i < 4; i++) {
#pragma unroll
      for (int j = 0; j < 4; j++) {
#pragma unroll
        for (int r = 0; r < 4; r++) {
          int m = m0 + wm + i * 16 + (lane >> 4) * 4 + r;
          int n = n0 + wn + j * 16 + arow;
          float v = acc[i][j][r];
          int bb = m >> 11, srow = m & (S_ - 1);
          int h = n >> 6, d = n & 63;
          size_t oidx = ((size_t)(bb * H_ + h) * S_ + srow) * HD_ + d;
          float other = __shfl_xor(v, 1, 64);   // n bit0 == lane bit0
          int fq = d >> 1;
          float2 cssn = *reinterpret_cast<const float2*>(tab + (srow * 32 + fq) * 2);
          float rv = (d & 1) ? (other * cssn.y + v * cssn.x)
                             : (v * cssn.x - other * cssn.y);
          if (z == 0) rv *= SCL2;   // pre-scale Q: logits in exp2 domain
          ((z == 0) ? Cq : Ck)[oidx] = (__bf16)rv;
        }
      }
    }
  }
}

// O-projection: same m97 structure with BK=64 two-subtile staging; fp32 out.
__global__ __launch_bounds__(256) void gemm_bt0(
    const __bf16* __restrict__ A, const __bf16* __restrict__ W0,
    float* __restrict__ Cf) {
  __shared__ __attribute__((aligned(16))) __bf16 As[2][128 * 32];
  __shared__ __attribute__((aligned(16))) __bf16 Bs[2][128 * 32];
  const int tid  = threadIdx.x;
  const int lane = tid & 63;
  const int wv   = tid >> 6;
  const int m0 = blockIdx.x * 128;
  const int n0 = blockIdx.y * 128;
  const int wm = (wv >> 1) * 64, wn = (wv & 1) * 64;
  const int arow = lane & 15;
  const int kgrp = (lane >> 4) * 8;

  f32x4 acc[4][4];
#pragma unroll
  for (int i = 0; i < 4; i++)
#pragma unroll
    for (int j = 0; j < 4; j++) acc[i][j] = f32x4{0.f, 0.f, 0.f, 0.f};

  for (int k0 = 0; k0 < 1024; k0 += 64) {
    __syncthreads();
#pragma unroll
    for (int hh = 0; hh < 2; ++hh) {
#pragma unroll
      for (int j = 0; j < 2; ++j) {
        int c   = (wv * 2 + j) * 64 + lane;
        int row = c >> 2;
        int kc  = (c & 3) * 8;
        gload_lds16(A + (size_t)(m0 + row) * 1024 + k0 + hh * 32 + kc,
                    As[hh] + (size_t)(wv * 2 + j) * 512);
        gload_lds16(W0 + (size_t)(n0 + row) * 1024 + k0 + hh * 32 + kc,
                    Bs[hh] + (size_t)(wv * 2 + j) * 512);
      }
    }
    asm volatile("s_waitcnt vmcnt(0)" ::: "memory");
    __syncthreads();
#pragma unroll
    for (int hh = 0; hh < 2; ++hh) {
      bf16x8 af[4], bw[4];
#pragma unroll
      for (int i = 0; i < 4; i++)
        af[i] = *reinterpret_cast<const bf16x8*>(As[hh] + (wm + i * 16 + arow) * 32 + kgrp);
#pragma unroll
      for (int i = 0; i < 4; i++)
        bw[i] = *reinterpret_cast<const bf16x8*>(Bs[hh] + (wn + i * 16 + arow) * 32 + kgrp);
#pragma unroll
      for (int i = 0; i < 4; i++)
#pragma unroll
        for (int j = 0; j < 4; j++)
          acc[i][j] = __builtin_amdgcn_mfma_f32_16x16x32_bf16(af[i], bw[j], acc[i][j], 0, 0, 0);
    }
  }

#pragma unroll
  for (int i = 0; i < 4; i++)
#pragma unroll
    for (int j = 0; j < 4; j++)
#pragma unroll
      for (int r = 0; r < 4; r++) {
        int m = m0 + wm + i * 16 + (lane >> 4) * 4 + r;
        int n = n0 + wn + j * 16 + arow;
        Cf[(size_t)m * D_ + n] = acc[i][j][r];
      }
}

// ---------------------------------------------------------------------------
// Flash attention, causal. Grid: (bh=32, pr=16). Block: 4 waves x 16 q-rows,
// paired q-tiles (pr, 31-pr) => uniform 17 kv-iters (KVBLK=128 keys/iter).
// Swapped QK^T (P lane-local). K LDS [128 key][64 d] with key-permutation
// (incl. 64-offset bit) so each lane's 32 P-values are exactly the 4 PV
// B-fragments; V LDS [64 d][128 key], row stride 256B, (d&7)<<4 XOR swizzle.
// Staging: linear-dest global_load_lds + inverse-swizzled source; counted
// vmcnt(8) double-buffer pipeline (proven pattern).
// ---------------------------------------------------------------------------
__global__ __launch_bounds__(256, 2) void attn_kernel(
    const __bf16* __restrict__ Q, const __bf16* __restrict__ K,
    const __bf16* __restrict__ Vt, __bf16* __restrict__ O) {
  __shared__ __attribute__((aligned(16))) __bf16 Ks[2][128 * 64];
  __shared__ __attribute__((aligned(16))) __bf16 Vs[2][64 * 128];
  const int tid = threadIdx.x, lane = tid & 63, wv = tid >> 6;
  const int bh = blockIdx.x;   // linear id stride 32 => all pr of a bh share an XCD
  const int pr = blockIdx.y;
  const int b = bh >> 4, h = bh & 15;
  const __bf16* Qb  = Q  + (size_t)bh * S_ * HD_;
  const __bf16* Kb  = K  + (size_t)bh * S_ * HD_;
  const __bf16* Vtb = Vt + (size_t)bh * HD_ * S_;
  const int arow = lane & 15, g = lane >> 4;

  // 8 gload_lds16 per thread per 128-key tile (4 K-chunks + 4 V-chunks)
#define STAGE(K0, BK_, BV_)                                                   \
  do {                                                                        \
    _Pragma("unroll") for (int j = 0; j < 4; ++j) {                           \
      int c = (wv * 4 + j) * 64 + lane;          /* chunk 0..1023 */          \
      int rowk = c >> 3, qqk = c & 7;                                         \
      int qsk = qqk ^ (rowk & 7);                                             \
      int ctp = rowk >> 4, rw = rowk & 15;                                    \
      int kph = ((ctp & 4) << 4) + ((ctp & 2) << 4) + ((ctp & 1) << 2)        \
                + ((rw >> 2) << 3) + (rw & 3);                                \
      gload_lds16(Kb + (size_t)((K0) + kph) * HD_ + qsk * 8,                  \
                  (BK_) + (size_t)(wv * 4 + j) * 512);                        \
      int rowv = c >> 4, qqv = c & 15;                                        \
      int qsv = qqv ^ (rowv & 7);                                             \
      gload_lds16(Vtb + (size_t)rowv * S_ + (K0) + qsv * 8,                   \
                  (BV_) + (size_t)(wv * 4 + j) * 512);                        \
    }                                                                         \
  } while (0)

  for (int seg = 0; seg < 2; ++seg) {
    const int qt = (seg == 0) ? pr : 31 - pr;   // 64-row q-tile index
    const int q0 = qt * 64;
    const int nkv = (qt >> 1) + 1;              // 128-key tiles
    const int qw = q0 + wv * 16;
    const int qg = qw + arow;                   // this thread's q-row

    bf16x8 aq[2];
#pragma unroll
    for (int j = 0; j < 2; j++)
      aq[j] = *reinterpret_cast<const bf16x8*>(
          Qb + (size_t)(qw + arow) * HD_ + j * 32 + g * 8);

    f32x4 po[4];
#pragma unroll
    for (int dt = 0; dt < 4; dt++) po[dt] = f32x4{0.f, 0.f, 0.f, 0.f};
    float mrow = -1e30f, lrow = 0.f;

    // prologue: stage tiles 0 and 1 (clamped); vmcnt(8) -> tile 0 landed
    STAGE(0, Ks[0], Vs[0]);
    {
      int t1 = (nkv > 1) ? 128 : 0;
      STAGE(t1, Ks[1], Vs[1]);
    }
    asm volatile("s_waitcnt vmcnt(8)" ::: "memory");
    __builtin_amdgcn_s_barrier();

    for (int kt = 0; kt < nkv; ++kt) {
      const int k0 = kt * 128;
      const int cur = kt & 1;
      const __bf16* Kc = Ks[cur];
      const __bf16* Vc = Vs[cur];

      // S^T = K Q^T : D[key][q], 16 MFMA over 128 keys
      f32x4 sc4[8];
      __builtin_amdgcn_s_setprio(1);
#pragma unroll
      for (int ct = 0; ct < 8; ct++) {
        sc4[ct] = f32x4{0.f, 0.f, 0.f, 0.f};
        int L = ct * 16 + arow;
#pragma unroll
        for (int j2 = 0; j2 < 2; j2++) {
          int byt = (L * 128 + j2 * 64 + g * 16) ^ ((L & 7) << 4);
          bf16x8 kb = *reinterpret_cast<const bf16x8*>((const char*)Kc + byt);
          sc4[ct] = __builtin_amdgcn_mfma_f32_16x16x32_bf16(kb, aq[j2], sc4[ct], 0, 0, 0);
        }
      }
      __builtin_amdgcn_s_setprio(0);

      // causal mask (last tile only). physical key of sc4[ct][r]:
      // k0 + (ct&4)*16 + (ct&2)*16 + (ct&1)*4 + g*8 + r
      if (kt == nkv - 1) {
#pragma unroll
        for (int ct = 0; ct < 8; ct++) {
          int kb0 = k0 + ((ct & 4) << 4) + ((ct & 2) << 4) + ((ct & 1) << 2) + g * 8;
#pragma unroll
          for (int r = 0; r < 4; r++)
            if (kb0 + r > qg) sc4[ct][r] = -1e30f;
        }
      }

      // in-register online softmax (one q-row per lane, 32 values)
      float mx = -1e30f;
#pragma unroll
      for (int ct = 0; ct < 8; ct++)
#pragma unroll
        for (int r = 0; r < 4; r++) mx = fmaxf(mx, sc4[ct][r]);
      mx = fmaxf(mx, __shfl_xor(mx, 16, 64));
      mx = fmaxf(mx, __shfl_xor(mx, 32, 64));

      bool noskip = !__all(mx <= mrow + 11.0f);
      if (noskip) {
        float mnew = fmaxf(mrow, mx);
        float corr = fexp2(mrow - mnew);
        mrow = mnew;
        lrow *= corr;
#pragma unroll
        for (int dt = 0; dt < 4; dt++)
#pragma unroll
          for (int r = 0; r < 4; r++) po[dt][r] *= corr;
      }

      float rs = 0.f;
#pragma unroll
      for (int ct = 0; ct < 8; ct++)
#pragma unroll
        for (int r = 0; r < 4; r++) {
          float e = fexp2(sc4[ct][r] - mrow);
          sc4[ct][r] = e;            // overwrite in place (VGPR economy)
          rs += e;
        }
      rs += __shfl_xor(rs, 16, 64);
      rs += __shfl_xor(rs, 32, 64);
      lrow += rs;

      // pack P: pb[jj] holds physical keys jj*32 + g*8 .. +7 (lane-local)
      bf16x8 pb[4];
#pragma unroll
      for (int h2 = 0; h2 < 2; h2++)
#pragma unroll
        for (int j2 = 0; j2 < 2; j2++) {
#pragma unroll
          for (int r = 0; r < 4; r++) {
            pb[h2 * 2 + j2][r]     = (__bf16)sc4[h2 * 4 + 2 * j2][r];
            pb[h2 * 2 + j2][4 + r] = (__bf16)sc4[h2 * 4 + 2 * j2 + 1][r];
          }
        }

      // O^T += V^T P^T : po[dt] = D[d][q], d = dt*16 + g*4 + r, q = arow
      __builtin_amdgcn_s_setprio(1);
#pragma unroll
      for (int dt = 0; dt < 4; dt++) {
        int d = dt * 16 + arow;
#pragma unroll
        for (int jj = 0; jj < 4; jj++) {
          int byv = (d * 256 + jj * 64 + g * 16) ^ ((d & 7) << 4);
          bf16x8 vb = *reinterpret_cast<const bf16x8*>((const char*)Vc + byv);
          po[dt] = __builtin_amdgcn_mfma_f32_16x16x32_bf16(vb, pb[jj], po[dt], 0, 0, 0);
        }
      }
      __builtin_amdgcn_s_setprio(0);

      // pipeline tail: all waves done reading buf[cur], then stage kt+2
      __builtin_amdgcn_s_barrier();
      if (kt < nkv - 1) {
        int nx = kt + 2;
        if (nx > nkv - 1) nx = nkv - 1;       // clamp: uniform 8-load count
        STAGE(nx * 128, Ks[cur], Vs[cur]);    // overwrite retired buffer
        asm volatile("s_waitcnt vmcnt(8)" ::: "memory");  // tile kt+1 landed
      } else {
        asm volatile("s_waitcnt vmcnt(0)" ::: "memory");  // drain for next seg
      }
      __builtin_amdgcn_s_barrier();
    }

    float inv = __builtin_amdgcn_rcpf(lrow);
#pragma unroll
    for (int dt = 0; dt < 4; dt++) {
      bf16x4 o4;
#pragma unroll
      for (int r = 0; r < 4; r++) o4[r] = (__bf16)(po[dt][r] * inv);
      *reinterpret_cast<bf16x4*>(
          O + (size_t)(b * S_ + qg) * D_ + h * HD_ + dt * 16 + g * 4) = o4;
    }
  }
#undef STAGE
}

extern "C" void kernel_launch(void* const* d_in, const int* in_sizes, int n_in,
                              void* d_out, int out_size, void* d_ws, size_t ws_size,
                              hipStream_t stream) {
  const float* x  = (const float*)d_in[0];
  const float* wq = (const float*)d_in[1];
  const float* wk = (const float*)d_in[2];
  const float* wv = (const float*)d_in[3];
  const float* wo = (const float*)d_in[4];
  float* out = (float*)d_out;

  char* w = (char*)d_ws;
  __bf16* xb  = (__bf16*)(w);                    // 8 MB
  __bf16* wqb = (__bf16*)(w + (8u  << 20));      // 2 MB each
  __bf16* wkb = (__bf16*)(w + (10u << 20));
  __bf16* wvb = (__bf16*)(w + (12u << 20));
  __bf16* wob = (__bf16*)(w + (14u << 20));
  __bf16* qws = (__bf16*)(w + (16u << 20));      // 8 MB each
  __bf16* kws = (__bf16*)(w + (24u << 20));
  __bf16* vtw = (__bf16*)(w + (32u << 20));      // V, stored TRANSPOSED [bh][d][s]
  __bf16* aws = (__bf16*)(w + (40u << 20));      // attn out, [token][feature]
  float*  tab = (float*)(w + (48u << 20));       // 512 KB rope table

  cvt_all_kernel<<<8448, 256, 0, stream>>>(x, wq, wk, wv, wo,
                                           xb, wqb, wkb, wvb, wob, tab);
  gemm_qkv<<<dim3(32, 8, 3), 256, 0, stream>>>(xb, wqb, wkb, wvb,
                                               qws, kws, vtw, tab);
  attn_kernel<<<dim3(2 * H_, S_ / 128), 256, 0, stream>>>(qws, kws, vtw, aws);
  gemm_bt0<<<dim3(M_ / 128, D_ / 128), 256, 0, stream>>>(aws, wob, out);
}

// Round 11
// 106.694 us; speedup vs baseline: 1.3720x; 1.1173x over previous
//
#include <hip/hip_runtime.h>
#include <hip/hip_bf16.h>
#include <stdint.h>

typedef __attribute__((ext_vector_type(4))) float f32x4;
typedef __attribute__((ext_vector_type(8))) __bf16 bf16x8;
typedef __attribute__((ext_vector_type(4))) __bf16 bf16x4;

#define DEVI __device__ __forceinline__

static constexpr int S_  = 2048;
static constexpr int D_  = 1024;
static constexpr int H_  = 16;
static constexpr int HD_ = 64;
static constexpr int M_  = 2 * S_;   // B*S = 4096 token rows
static constexpr float SCL2 = 0.18033688f;  // 0.125 * log2(e)

DEVI void gload_lds16(const void* gsrc, void* ldst) {
  __builtin_amdgcn_global_load_lds(
      (__attribute__((address_space(1))) void*)(void*)gsrc,
      (__attribute__((address_space(3))) void*)ldst, 16, 0, 0);
}

DEVI float fexp2(float x) {
  float r;
  asm("v_exp_f32 %0, %1" : "=v"(r) : "v"(x));
  return r;
}

// One fused conversion kernel: x + 4 weights fp32->bf16, plus RoPE table.
__global__ __launch_bounds__(256) void cvt_all_kernel(
    const float* __restrict__ x, const float* __restrict__ wq,
    const float* __restrict__ wk, const float* __restrict__ wv,
    const float* __restrict__ wo,
    __bf16* __restrict__ xb, __bf16* __restrict__ wqb,
    __bf16* __restrict__ wkb, __bf16* __restrict__ wvb,
    __bf16* __restrict__ wob, float* __restrict__ tab) {
  int blk = blockIdx.x;
  if (blk < 8192) {
    int i = blk * 256 + threadIdx.x;     // float4 index
    const float* src; __bf16* dst; int off;
    if (i < (1 << 20))                      { src = x;  dst = xb;  off = 0; }
    else if (i < (1 << 20) + (1 << 18))     { src = wq; dst = wqb; off = (1 << 20); }
    else if (i < (1 << 20) + 2 * (1 << 18)) { src = wk; dst = wkb; off = (1 << 20) + (1 << 18); }
    else if (i < (1 << 20) + 3 * (1 << 18)) { src = wv; dst = wvb; off = (1 << 20) + 2 * (1 << 18); }
    else                                    { src = wo; dst = wob; off = (1 << 20) + 3 * (1 << 18); }
    int j = i - off;
    float4 v = reinterpret_cast<const float4*>(src)[j];
    bf16x4 o;
    o[0] = (__bf16)v.x; o[1] = (__bf16)v.y; o[2] = (__bf16)v.z; o[3] = (__bf16)v.w;
    reinterpret_cast<bf16x4*>(dst)[j] = o;
  } else {
    int i = (blk - 8192) * 256 + threadIdx.x;   // 0..65535 = S*32
    int s = i >> 5, f = i & 31;
    float freq = powf(10000.0f, -(float)(2 * f) / (float)HD_);
    float ang = (float)s * freq;
    tab[2 * i]     = cosf(ang);
    tab[2 * i + 1] = sinf(ang);
  }
}

// ---------------------------------------------------------------------------
// QKV GEMM: m97 128x128 BK=32 structure, now 512-thread / 8-wave blocks
// (wave grid 2M x 4N, each wave 64x32 output). Identical staging pattern,
// LDS layout, fragment reads, and epilogues to the proven 4-wave kernel --
// only the per-wave ownership changed. Grid 768 -> 24 waves/CU (vs 12):
// doubles the independent waves available to hide the per-iter drain.
// z=0/1 -> RoPE + head-split (Q pre-scaled by SCL2);
// z=2 -> V written DIRECTLY TRANSPOSED as Vt[bh][d][s].
// ---------------------------------------------------------------------------
__global__ __launch_bounds__(512, 6) void gemm_qkv(
    const __bf16* __restrict__ A, const __bf16* __restrict__ W0,
    const __bf16* __restrict__ W1, const __bf16* __restrict__ W2,
    __bf16* __restrict__ Cq, __bf16* __restrict__ Ck, __bf16* __restrict__ Cvt,
    const float* __restrict__ tab) {
  __shared__ __attribute__((aligned(16))) __bf16 As[128 * 32];
  __shared__ __attribute__((aligned(16))) __bf16 Bs[128 * 32];
  const int tid  = threadIdx.x;
  const int lane = tid & 63;
  const int wv   = tid >> 6;           // 0..7
  const int wr   = wv >> 2;            // 0..1 (M strip of 64)
  const int wc   = wv & 3;             // 0..3 (N strip of 32)
  const int m0 = blockIdx.x * 128;
  const int n0 = blockIdx.y * 128;
  const int z  = blockIdx.z;
  const __bf16* W = (z == 0) ? W0 : (z == 1 ? W1 : W2);
  const int arow = lane & 15;
  const int kgrp = (lane >> 4) * 8;

  f32x4 acc[4][2];
#pragma unroll
  for (int i = 0; i < 4; i++)
#pragma unroll
    for (int j = 0; j < 2; j++) acc[i][j] = f32x4{0.f, 0.f, 0.f, 0.f};

  for (int k0 = 0; k0 < 1024; k0 += 32) {
    __syncthreads();
    {
      int c   = wv * 64 + lane;        // chunk 0..511 (whole tile)
      int row = c >> 2;
      int kc  = (c & 3) * 8;
      gload_lds16(A + (size_t)(m0 + row) * 1024 + k0 + kc, As + wv * 512);
      gload_lds16(W + (size_t)(n0 + row) * 1024 + k0 + kc, Bs + wv * 512);
    }
    asm volatile("s_waitcnt vmcnt(0)" ::: "memory");
    __syncthreads();
    bf16x8 af[4], bw[2];
#pragma unroll
    for (int i = 0; i < 4; i++)
      af[i] = *reinterpret_cast<const bf16x8*>(As + (wr * 64 + i * 16 + arow) * 32 + kgrp);
#pragma unroll
    for (int j = 0; j < 2; j++)
      bw[j] = *reinterpret_cast<const bf16x8*>(Bs + (wc * 32 + j * 16 + arow) * 32 + kgrp);
#pragma unroll
    for (int i = 0; i < 4; i++)
#pragma unroll
      for (int j = 0; j < 2; j++)
        acc[i][j] = __builtin_amdgcn_mfma_f32_16x16x32_bf16(af[i], bw[j], acc[i][j], 0, 0, 0);
  }

  // epilogue. C/D layout: col = lane&15 (n), row = (lane>>4)*4 + r (m)
  if (z == 2) {
#pragma unroll
    for (int i = 0; i < 4; i++) {
      int m = m0 + wr * 64 + i * 16 + (lane >> 4) * 4;
      int bb = m >> 11, srow = m & (S_ - 1);
#pragma unroll
      for (int j = 0; j < 2; j++) {
        int n = n0 + wc * 32 + j * 16 + arow;
        int h = n >> 6, d = n & 63;
        bf16x4 o4;
#pragma unroll
        for (int r = 0; r < 4; r++) o4[r] = (__bf16)acc[i][j][r];
        *reinterpret_cast<bf16x4*>(
            Cvt + ((size_t)(bb * H_ + h) * HD_ + d) * S_ + srow) = o4;
      }
    }
  } else {
#pragma unroll
    for (int i = 0; i < 4; i++) {
#pragma unroll
      for (int j = 0; j < 2; j++) {
#pragma unroll
        for (int r = 0; r < 4; r++) {
          int m = m0 + wr * 64 + i * 16 + (lane >> 4) * 4 + r;
          int n = n0 + wc * 32 + j * 16 + arow;
          float v = acc[i][j][r];
          int bb = m >> 11, srow = m & (S_ - 1);
          int h = n >> 6, d = n & 63;
          size_t oidx = ((size_t)(bb * H_ + h) * S_ + srow) * HD_ + d;
          float other = __shfl_xor(v, 1, 64);   // n bit0 == lane bit0
          int fq = d >> 1;
          float2 cssn = *reinterpret_cast<const float2*>(tab + (srow * 32 + fq) * 2);
          float rv = (d & 1) ? (other * cssn.y + v * cssn.x)
                             : (v * cssn.x - other * cssn.y);
          if (z == 0) rv *= SCL2;   // pre-scale Q: logits in exp2 domain
          ((z == 0) ? Cq : Ck)[oidx] = (__bf16)rv;
        }
      }
    }
  }
}

// ---------------------------------------------------------------------------
// O-projection: tile 128x64, 512-thread / 8-wave blocks (wave grid 4M x 2N,
// each wave 32x32). Grid (32,16) = 512 blocks = 2 blocks/CU = 16 waves/CU
// (vs 4 before). B staged by waves 0..3 (wave-uniform conditional). fp32 out.
// ---------------------------------------------------------------------------
__global__ __launch_bounds__(512, 4) void gemm_bt0(
    const __bf16* __restrict__ A, const __bf16* __restrict__ W0,
    float* __restrict__ Cf) {
  __shared__ __attribute__((aligned(16))) __bf16 As[128 * 32];
  __shared__ __attribute__((aligned(16))) __bf16 Bs[64 * 32];
  const int tid  = threadIdx.x;
  const int lane = tid & 63;
  const int wv   = tid >> 6;
  const int wr   = wv >> 1;            // 0..3 (M strip of 32)
  const int wc   = wv & 1;             // 0..1 (N strip of 32)
  const int m0 = blockIdx.x * 128;
  const int n0 = blockIdx.y * 64;
  const int arow = lane & 15;
  const int kgrp = (lane >> 4) * 8;

  f32x4 acc[2][2];
#pragma unroll
  for (int i = 0; i < 2; i++)
#pragma unroll
    for (int j = 0; j < 2; j++) acc[i][j] = f32x4{0.f, 0.f, 0.f, 0.f};

  for (int k0 = 0; k0 < 1024; k0 += 32) {
    __syncthreads();
    {
      int c   = wv * 64 + lane;        // 0..511 -> A rows 0..127
      int row = c >> 2;
      int kc  = (c & 3) * 8;
      gload_lds16(A + (size_t)(m0 + row) * 1024 + k0 + kc, As + wv * 512);
      if (wv < 4)                      // 0..255 -> B rows 0..63
        gload_lds16(W0 + (size_t)(n0 + row) * 1024 + k0 + kc, Bs + wv * 512);
    }
    asm volatile("s_waitcnt vmcnt(0)" ::: "memory");
    __syncthreads();
    bf16x8 af[2], bw[2];
#pragma unroll
    for (int i = 0; i < 2; i++)
      af[i] = *reinterpret_cast<const bf16x8*>(As + (wr * 32 + i * 16 + arow) * 32 + kgrp);
#pragma unroll
    for (int j = 0; j < 2; j++)
      bw[j] = *reinterpret_cast<const bf16x8*>(Bs + (wc * 32 + j * 16 + arow) * 32 + kgrp);
#pragma unroll
    for (int i = 0; i < 2; i++)
#pragma unroll
      for (int j = 0; j < 2; j++)
        acc[i][j] = __builtin_amdgcn_mfma_f32_16x16x32_bf16(af[i], bw[j], acc[i][j], 0, 0, 0);
  }

#pragma unroll
  for (int i = 0; i < 2; i++)
#pragma unroll
    for (int j = 0; j < 2; j++)
#pragma unroll
      for (int r = 0; r < 4; r++) {
        int m = m0 + wr * 32 + i * 16 + (lane >> 4) * 4 + r;
        int n = n0 + wc * 32 + j * 16 + arow;
        Cf[(size_t)m * D_ + n] = acc[i][j][r];
      }
}

// ---------------------------------------------------------------------------
// Flash attention, causal. Grid: (bh=32, pr=16). Block: 4 waves x 16 q-rows,
// paired q-tiles (pr, 31-pr) => uniform 17 kv-iters (KVBLK=128 keys/iter).
// Swapped QK^T (P lane-local). K LDS [128 key][64 d] with key-permutation
// (incl. 64-offset bit) so each lane's 32 P-values are exactly the 4 PV
// B-fragments; V LDS [64 d][128 key], row stride 256B, (d&7)<<4 XOR swizzle.
// Staging: linear-dest global_load_lds + inverse-swizzled source; counted
// vmcnt(8) double-buffer pipeline (proven pattern).
// ---------------------------------------------------------------------------
__global__ __launch_bounds__(256, 2) void attn_kernel(
    const __bf16* __restrict__ Q, const __bf16* __restrict__ K,
    const __bf16* __restrict__ Vt, __bf16* __restrict__ O) {
  __shared__ __attribute__((aligned(16))) __bf16 Ks[2][128 * 64];
  __shared__ __attribute__((aligned(16))) __bf16 Vs[2][64 * 128];
  const int tid = threadIdx.x, lane = tid & 63, wv = tid >> 6;
  const int bh = blockIdx.x;   // linear id stride 32 => all pr of a bh share an XCD
  const int pr = blockIdx.y;
  const int b = bh >> 4, h = bh & 15;
  const __bf16* Qb  = Q  + (size_t)bh * S_ * HD_;
  const __bf16* Kb  = K  + (size_t)bh * S_ * HD_;
  const __bf16* Vtb = Vt + (size_t)bh * HD_ * S_;
  const int arow = lane & 15, g = lane >> 4;

  // 8 gload_lds16 per thread per 128-key tile (4 K-chunks + 4 V-chunks)
#define STAGE(K0, BK_, BV_)                                                   \
  do {                                                                        \
    _Pragma("unroll") for (int j = 0; j < 4; ++j) {                           \
      int c = (wv * 4 + j) * 64 + lane;          /* chunk 0..1023 */          \
      int rowk = c >> 3, qqk = c & 7;                                         \
      int qsk = qqk ^ (rowk & 7);                                             \
      int ctp = rowk >> 4, rw = rowk & 15;                                    \
      int kph = ((ctp & 4) << 4) + ((ctp & 2) << 4) + ((ctp & 1) << 2)        \
                + ((rw >> 2) << 3) + (rw & 3);                                \
      gload_lds16(Kb + (size_t)((K0) + kph) * HD_ + qsk * 8,                  \
                  (BK_) + (size_t)(wv * 4 + j) * 512);                        \
      int rowv = c >> 4, qqv = c & 15;                                        \
      int qsv = qqv ^ (rowv & 7);                                             \
      gload_lds16(Vtb + (size_t)rowv * S_ + (K0) + qsv * 8,                   \
                  (BV_) + (size_t)(wv * 4 + j) * 512);                        \
    }                                                                         \
  } while (0)

  for (int seg = 0; seg < 2; ++seg) {
    const int qt = (seg == 0) ? pr : 31 - pr;   // 64-row q-tile index
    const int q0 = qt * 64;
    const int nkv = (qt >> 1) + 1;              // 128-key tiles
    const int qw = q0 + wv * 16;
    const int qg = qw + arow;                   // this thread's q-row

    bf16x8 aq[2];
#pragma unroll
    for (int j = 0; j < 2; j++)
      aq[j] = *reinterpret_cast<const bf16x8*>(
          Qb + (size_t)(qw + arow) * HD_ + j * 32 + g * 8);

    f32x4 po[4];
#pragma unroll
    for (int dt = 0; dt < 4; dt++) po[dt] = f32x4{0.f, 0.f, 0.f, 0.f};
    float mrow = -1e30f, lrow = 0.f;

    // prologue: stage tiles 0 and 1 (clamped); vmcnt(8) -> tile 0 landed
    STAGE(0, Ks[0], Vs[0]);
    {
      int t1 = (nkv > 1) ? 128 : 0;
      STAGE(t1, Ks[1], Vs[1]);
    }
    asm volatile("s_waitcnt vmcnt(8)" ::: "memory");
    __builtin_amdgcn_s_barrier();

    for (int kt = 0; kt < nkv; ++kt) {
      const int k0 = kt * 128;
      const int cur = kt & 1;
      const __bf16* Kc = Ks[cur];
      const __bf16* Vc = Vs[cur];

      // S^T = K Q^T : D[key][q], 16 MFMA over 128 keys
      f32x4 sc4[8];
      __builtin_amdgcn_s_setprio(1);
#pragma unroll
      for (int ct = 0; ct < 8; ct++) {
        sc4[ct] = f32x4{0.f, 0.f, 0.f, 0.f};
        int L = ct * 16 + arow;
#pragma unroll
        for (int j2 = 0; j2 < 2; j2++) {
          int byt = (L * 128 + j2 * 64 + g * 16) ^ ((L & 7) << 4);
          bf16x8 kb = *reinterpret_cast<const bf16x8*>((const char*)Kc + byt);
          sc4[ct] = __builtin_amdgcn_mfma_f32_16x16x32_bf16(kb, aq[j2], sc4[ct], 0, 0, 0);
        }
      }
      __builtin_amdgcn_s_setprio(0);

      // causal mask (last tile only). physical key of sc4[ct][r]:
      // k0 + (ct&4)*16 + (ct&2)*16 + (ct&1)*4 + g*8 + r
      if (kt == nkv - 1) {
#pragma unroll
        for (int ct = 0; ct < 8; ct++) {
          int kb0 = k0 + ((ct & 4) << 4) + ((ct & 2) << 4) + ((ct & 1) << 2) + g * 8;
#pragma unroll
          for (int r = 0; r < 4; r++)
            if (kb0 + r > qg) sc4[ct][r] = -1e30f;
        }
      }

      // in-register online softmax (one q-row per lane, 32 values)
      float mx = -1e30f;
#pragma unroll
      for (int ct = 0; ct < 8; ct++)
#pragma unroll
        for (int r = 0; r < 4; r++) mx = fmaxf(mx, sc4[ct][r]);
      mx = fmaxf(mx, __shfl_xor(mx, 16, 64));
      mx = fmaxf(mx, __shfl_xor(mx, 32, 64));

      bool noskip = !__all(mx <= mrow + 11.0f);
      if (noskip) {
        float mnew = fmaxf(mrow, mx);
        float corr = fexp2(mrow - mnew);
        mrow = mnew;
        lrow *= corr;
#pragma unroll
        for (int dt = 0; dt < 4; dt++)
#pragma unroll
          for (int r = 0; r < 4; r++) po[dt][r] *= corr;
      }

      float rs = 0.f;
#pragma unroll
      for (int ct = 0; ct < 8; ct++)
#pragma unroll
        for (int r = 0; r < 4; r++) {
          float e = fexp2(sc4[ct][r] - mrow);
          sc4[ct][r] = e;            // overwrite in place (VGPR economy)
          rs += e;
        }
      rs += __shfl_xor(rs, 16, 64);
      rs += __shfl_xor(rs, 32, 64);
      lrow += rs;

      // pack P: pb[jj] holds physical keys jj*32 + g*8 .. +7 (lane-local)
      bf16x8 pb[4];
#pragma unroll
      for (int h2 = 0; h2 < 2; h2++)
#pragma unroll
        for (int j2 = 0; j2 < 2; j2++) {
#pragma unroll
          for (int r = 0; r < 4; r++) {
            pb[h2 * 2 + j2][r]     = (__bf16)sc4[h2 * 4 + 2 * j2][r];
            pb[h2 * 2 + j2][4 + r] = (__bf16)sc4[h2 * 4 + 2 * j2 + 1][r];
          }
        }

      // O^T += V^T P^T : po[dt] = D[d][q], d = dt*16 + g*4 + r, q = arow
      __builtin_amdgcn_s_setprio(1);
#pragma unroll
      for (int dt = 0; dt < 4; dt++) {
        int d = dt * 16 + arow;
#pragma unroll
        for (int jj = 0; jj < 4; jj++) {
          int byv = (d * 256 + jj * 64 + g * 16) ^ ((d & 7) << 4);
          bf16x8 vb = *reinterpret_cast<const bf16x8*>((const char*)Vc + byv);
          po[dt] = __builtin_amdgcn_mfma_f32_16x16x32_bf16(vb, pb[jj], po[dt], 0, 0, 0);
        }
      }
      __builtin_amdgcn_s_setprio(0);

      // pipeline tail: all waves done reading buf[cur], then stage kt+2
      __builtin_amdgcn_s_barrier();
      if (kt < nkv - 1) {
        int nx = kt + 2;
        if (nx > nkv - 1) nx = nkv - 1;       // clamp: uniform 8-load count
        STAGE(nx * 128, Ks[cur], Vs[cur]);    // overwrite retired buffer
        asm volatile("s_waitcnt vmcnt(8)" ::: "memory");  // tile kt+1 landed
      } else {
        asm volatile("s_waitcnt vmcnt(0)" ::: "memory");  // drain for next seg
      }
      __builtin_amdgcn_s_barrier();
    }

    float inv = __builtin_amdgcn_rcpf(lrow);
#pragma unroll
    for (int dt = 0; dt < 4; dt++) {
      bf16x4 o4;
#pragma unroll
      for (int r = 0; r < 4; r++) o4[r] = (__bf16)(po[dt][r] * inv);
      *reinterpret_cast<bf16x4*>(
          O + (size_t)(b * S_ + qg) * D_ + h * HD_ + dt * 16 + g * 4) = o4;
    }
  }
#undef STAGE
}

extern "C" void kernel_launch(void* const* d_in, const int* in_sizes, int n_in,
                              void* d_out, int out_size, void* d_ws, size_t ws_size,
                              hipStream_t stream) {
  const float* x  = (const float*)d_in[0];
  const float* wq = (const float*)d_in[1];
  const float* wk = (const float*)d_in[2];
  const float* wv = (const float*)d_in[3];
  const float* wo = (const float*)d_in[4];
  float* out = (float*)d_out;

  char* w = (char*)d_ws;
  __bf16* xb  = (__bf16*)(w);                    // 8 MB
  __bf16* wqb = (__bf16*)(w + (8u  << 20));      // 2 MB each
  __bf16* wkb = (__bf16*)(w + (10u << 20));
  __bf16* wvb = (__bf16*)(w + (12u << 20));
  __bf16* wob = (__bf16*)(w + (14u << 20));
  __bf16* qws = (__bf16*)(w + (16u << 20));      // 8 MB each
  __bf16* kws = (__bf16*)(w + (24u << 20));
  __bf16* vtw = (__bf16*)(w + (32u << 20));      // V, stored TRANSPOSED [bh][d][s]
  __bf16* aws = (__bf16*)(w + (40u << 20));      // attn out, [token][feature]
  float*  tab = (float*)(w + (48u << 20));       // 512 KB rope table

  cvt_all_kernel<<<8448, 256, 0, stream>>>(x, wq, wk, wv, wo,
                                           xb, wqb, wkb, wvb, wob, tab);
  gemm_qkv<<<dim3(32, 8, 3), 512, 0, stream>>>(xb, wqb, wkb, wvb,
                                               qws, kws, vtw, tab);
  attn_kernel<<<dim3(2 * H_, S_ / 128), 256, 0, stream>>>(qws, kws, vtw, aws);
  gemm_bt0<<<dim3(M_ / 128, D_ / 64), 512, 0, stream>>>(aws, wob, out);
}